// Round 5
// baseline (735.599 us; speedup 1.0000x reference)
//
#include <hip/hip_runtime.h>
#include <hip/hip_cooperative_groups.h>

namespace cg = cooperative_groups;

// ---------------------------------------------------------------------------
// Workspace:
//   idxb 0        : (2048,100) int       819200
//   sdn  819200   : (6,3,128)              9216
//   stp  828416   : 6 layers x 32 banks x 256 f32  196608   (BN partials)
//   fo   1025024  : 3 x (2048,256)       6291456
//   p0.. 7316480  : 6 x (2048,128)       6291456  (p_k = pb + k*262144 floats)
// r5: mega (K2..K6, cooperative, 512 blocks) with explicit __threadfence()
// around each grid.sync (cross-XCD L2 release/acquire) + host-side fallback
// to the verified r2 multi-launch sequence if the coop enqueue is rejected.
// ---------------------------------------------------------------------------

// ---------------------------------------------------------------------------
// GEMM body (chunked-LDS W, 16KB chunks): out[r0..r0+7, :256] =
// bn_relu?(in) @ W + bias. 8 rows/block, 256 threads = 2 rows x 4 cols.
// LDS 21504B. [r1 lesson: no reg-prefetch across barriers]
// ---------------------------------------------------------------------------
__device__ __forceinline__ void do_gemm(
    const float* __restrict__ in, const float* __restrict__ stp,
    const float* __restrict__ gm, const float* __restrict__ bt,
    const float* __restrict__ W, const float* __restrict__ bi,
    float* __restrict__ out, int rb, char* smemc)
{
    float* rows  = (float*)smemc;           // 1024 floats
    float* wch   = rows + 1024;             // 4096 floats (16 KB)
    float* scale = wch + 4096;              // 128
    float* shift = scale + 128;             // 128
    int t = threadIdx.x;
    if (t < 128) {
        float sc = 1.0f, sf = 0.0f;
        if (stp) {
            float sm = 0.0f, sq = 0.0f;
            #pragma unroll 8
            for (int bk = 0; bk < 32; ++bk) {
                sm += stp[bk*256 + t];
                sq += stp[bk*256 + 128 + t];
            }
            float mu  = sm * (1.0f/2048.0f);
            float var = sq * (1.0f/2048.0f) - mu*mu;
            sc = rsqrtf(var + 1e-5f) * gm[t];
            sf = bt[t] - mu*sc;
        }
        scale[t] = sc; shift[t] = sf;
    }
    __syncthreads();
    int r0 = rb * 8;
    {
        float4 v = ((const float4*)(in + r0*128))[t];
        if (stp) {
            int c4 = (t & 31) << 2;
            v.x = fmaxf(v.x*scale[c4  ] + shift[c4  ], 0.0f);
            v.y = fmaxf(v.y*scale[c4+1] + shift[c4+1], 0.0f);
            v.z = fmaxf(v.z*scale[c4+2] + shift[c4+2], 0.0f);
            v.w = fmaxf(v.w*scale[c4+3] + shift[c4+3], 0.0f);
        }
        ((float4*)rows)[t] = v;
    }
    int cb = t & 63, rp = (t >> 6) << 1;
    const float* a0r = rows + rp*128;
    const float* a1r = a0r + 128;
    const float4* W4 = (const float4*)W;
    float4* wch4 = (float4*)wch;
    float4 acc0 = make_float4(0.f,0.f,0.f,0.f);
    float4 acc1 = make_float4(0.f,0.f,0.f,0.f);
    for (int c = 0; c < 8; ++c) {
        __syncthreads();
        #pragma unroll
        for (int i = 0; i < 4; ++i)
            wch4[t + 256*i] = W4[c*1024 + t + 256*i];
        __syncthreads();
        int kb = c*16;
        #pragma unroll
        for (int k = 0; k < 16; k += 4) {
            float4 a0 = *(const float4*)(a0r + kb + k);
            float4 a1 = *(const float4*)(a1r + kb + k);
            float4 w;
            w = wch4[(k+0)*64+cb];
            acc0.x += a0.x*w.x; acc0.y += a0.x*w.y; acc0.z += a0.x*w.z; acc0.w += a0.x*w.w;
            acc1.x += a1.x*w.x; acc1.y += a1.x*w.y; acc1.z += a1.x*w.z; acc1.w += a1.x*w.w;
            w = wch4[(k+1)*64+cb];
            acc0.x += a0.y*w.x; acc0.y += a0.y*w.y; acc0.z += a0.y*w.z; acc0.w += a0.y*w.w;
            acc1.x += a1.y*w.x; acc1.y += a1.y*w.y; acc1.z += a1.y*w.z; acc1.w += a1.y*w.w;
            w = wch4[(k+2)*64+cb];
            acc0.x += a0.z*w.x; acc0.y += a0.z*w.y; acc0.z += a0.z*w.z; acc0.w += a0.z*w.w;
            acc1.x += a1.z*w.x; acc1.y += a1.z*w.y; acc1.z += a1.z*w.z; acc1.w += a1.z*w.w;
            w = wch4[(k+3)*64+cb];
            acc0.x += a0.w*w.x; acc0.y += a0.w*w.y; acc0.z += a0.w*w.z; acc0.w += a0.w*w.w;
            acc1.x += a1.w*w.x; acc1.y += a1.w*w.y; acc1.z += a1.w*w.z; acc1.w += a1.w*w.w;
        }
    }
    float4 b4 = ((const float4*)bi)[cb];
    acc0.x += b4.x; acc0.y += b4.y; acc0.z += b4.z; acc0.w += b4.w;
    acc1.x += b4.x; acc1.y += b4.y; acc1.z += b4.z; acc1.w += b4.w;
    ((float4*)out)[(r0+rp  )*64 + cb] = acc0;
    ((float4*)out)[(r0+rp+1)*64 + cb] = acc1;
}

// ---------------------------------------------------------------------------
// Big-chunk GEMM body (fallback path, r2-verified): chunk = k64 (64KB).
// ---------------------------------------------------------------------------
__device__ __forceinline__ void do_gemm_big(
    const float* __restrict__ in, const float* __restrict__ stp,
    const float* __restrict__ gm, const float* __restrict__ bt,
    const float* __restrict__ W, const float* __restrict__ bi,
    float* __restrict__ out, int rb, char* smemc)
{
    float* rows  = (float*)smemc;           // 1024 floats
    float* wch   = rows + 1024;             // 16384 floats (64 KB)
    float* scale = wch + 16384;             // 128
    float* shift = scale + 128;             // 128
    int t = threadIdx.x;
    if (t < 128) {
        float sc = 1.0f, sf = 0.0f;
        if (stp) {
            float sm = 0.0f, sq = 0.0f;
            #pragma unroll 8
            for (int bk = 0; bk < 32; ++bk) {
                sm += stp[bk*256 + t];
                sq += stp[bk*256 + 128 + t];
            }
            float mu  = sm * (1.0f/2048.0f);
            float var = sq * (1.0f/2048.0f) - mu*mu;
            sc = rsqrtf(var + 1e-5f) * gm[t];
            sf = bt[t] - mu*sc;
        }
        scale[t] = sc; shift[t] = sf;
    }
    __syncthreads();
    int r0 = rb * 8;
    {
        float4 v = ((const float4*)(in + r0*128))[t];
        if (stp) {
            int c4 = (t & 31) << 2;
            v.x = fmaxf(v.x*scale[c4  ] + shift[c4  ], 0.0f);
            v.y = fmaxf(v.y*scale[c4+1] + shift[c4+1], 0.0f);
            v.z = fmaxf(v.z*scale[c4+2] + shift[c4+2], 0.0f);
            v.w = fmaxf(v.w*scale[c4+3] + shift[c4+3], 0.0f);
        }
        ((float4*)rows)[t] = v;
    }
    int cb = t & 63, rp = (t >> 6) << 1;
    const float* a0r = rows + rp*128;
    const float* a1r = a0r + 128;
    const float4* W4 = (const float4*)W;
    float4* wch4 = (float4*)wch;
    float4 acc0 = make_float4(0.f,0.f,0.f,0.f);
    float4 acc1 = make_float4(0.f,0.f,0.f,0.f);
    for (int c = 0; c < 2; ++c) {
        __syncthreads();
        #pragma unroll
        for (int i = 0; i < 16; ++i)
            wch4[t + 256*i] = W4[c*4096 + t + 256*i];
        __syncthreads();
        int kb = c*64;
        #pragma unroll 4
        for (int k = 0; k < 64; k += 4) {
            float4 a0 = *(const float4*)(a0r + kb + k);
            float4 a1 = *(const float4*)(a1r + kb + k);
            float4 w;
            w = wch4[(k+0)*64+cb];
            acc0.x += a0.x*w.x; acc0.y += a0.x*w.y; acc0.z += a0.x*w.z; acc0.w += a0.x*w.w;
            acc1.x += a1.x*w.x; acc1.y += a1.x*w.y; acc1.z += a1.x*w.z; acc1.w += a1.x*w.w;
            w = wch4[(k+1)*64+cb];
            acc0.x += a0.y*w.x; acc0.y += a0.y*w.y; acc0.z += a0.y*w.z; acc0.w += a0.y*w.w;
            acc1.x += a1.y*w.x; acc1.y += a1.y*w.y; acc1.z += a1.y*w.z; acc1.w += a1.y*w.w;
            w = wch4[(k+2)*64+cb];
            acc0.x += a0.z*w.x; acc0.y += a0.z*w.y; acc0.z += a0.z*w.z; acc0.w += a0.z*w.w;
            acc1.x += a1.z*w.x; acc1.y += a1.z*w.y; acc1.z += a1.z*w.z; acc1.w += a1.z*w.w;
            w = wch4[(k+3)*64+cb];
            acc0.x += a0.w*w.x; acc0.y += a0.w*w.y; acc0.z += a0.w*w.z; acc0.w += a0.w*w.w;
            acc1.x += a1.w*w.x; acc1.y += a1.w*w.y; acc1.z += a1.w*w.z; acc1.w += a1.w*w.w;
        }
    }
    float4 b4 = ((const float4*)bi)[cb];
    acc0.x += b4.x; acc0.y += b4.y; acc0.z += b4.z; acc0.w += b4.w;
    acc1.x += b4.x; acc1.y += b4.y; acc1.z += b4.z; acc1.w += b4.w;
    ((float4*)out)[(r0+rp  )*64 + cb] = acc0;
    ((float4*)out)[(r0+rp+1)*64 + cb] = acc1;
}

// ---------------------------------------------------------------------------
// Agg unit (verified r2 scalar body): 256 threads = 2 rows. Leading
// __syncthreads protects LDS reuse when a block runs multiple units.
// ---------------------------------------------------------------------------
__device__ __forceinline__ void agg_unit(
    const int* __restrict__ idx, const float* __restrict__ verts,
    const float* __restrict__ sdn, const float* __restrict__ fos,
    int n, int dI, float* __restrict__ outp, float* __restrict__ stp,
    int xblk, char* smemc)
{
    float4* ds4s = (float4*)smemc;              // 200 float4 (3200B)
    int* jss = (int*)(smemc + 3200);            // 200 int (800B)
    const float* sd = sdn + dI * 384;

    int t = threadIdx.x;
    int h = t >> 7, tt = t & 127;
    float4* ds4 = ds4s + h*100;
    int* js = jss + h*100;
    int r = xblk*2 + h;
    int b = r >> 10;

    __syncthreads();                            // protect LDS from prev unit
    if (tt < n) {
        int j = idx[r*100 + tt];
        js[tt] = j;
        const float* pj = verts + (b*1024 + j)*3;
        const float* pv = verts + r*3;
        float dx = pj[0]-pv[0], dy = pj[1]-pv[1], dz = pj[2]-pv[2];
        float nm = sqrtf(dx*dx + dy*dy + dz*dz);
        float inv = 1.0f / fmaxf(nm, 1e-12f);
        ds4[tt] = make_float4(dx*inv, dy*inv, dz*inv, 0.0f);
    }
    __syncthreads();
    float s0 = sd[tt], s1 = sd[128+tt], s2 = sd[256+tt];
    int bb = b * 1024;
    float m = -3.0e38f;
    for (int q = 0; q < n; q += 5) {
        float th[5];
        const float* p[5];
        #pragma unroll
        for (int u = 0; u < 5; ++u) {
            float4 dq = ds4[q+u];
            th[u] = fmaxf(dq.x*s0 + dq.y*s1 + dq.z*s2, 0.0f);
            p[u] = fos + (size_t)(bb + js[q+u])*256 + 128 + tt;
        }
        float vv[5];
        #pragma unroll
        for (int u = 0; u < 5; ++u) vv[u] = *p[u];
        #pragma unroll
        for (int u = 0; u < 5; ++u) m = fmaxf(m, th[u]*vv[u]);
    }
    float val = fos[r*256 + tt] + m;
    outp[r*128 + tt] = val;
    float* bank = stp + (r & 31)*256;
    atomicAdd(&bank[tt], val);
    atomicAdd(&bank[128+tt], val*val);
}

// ---------------------------------------------------------------------------
// K1: wave-sync knn (0..511) + gemmA (512..1279) + zero stp (1280..1471) +
// dirs norm (1472). knn algorithm verified r8-r12.
// ---------------------------------------------------------------------------
__global__ void k1_kernel(const float* __restrict__ verts, const float* __restrict__ dirs,
                          const float* __restrict__ x,
                          const float* __restrict__ convW, const float* __restrict__ convB,
                          int* __restrict__ idxout, float* __restrict__ sdn,
                          float* __restrict__ stp, float* __restrict__ fo)
{
    __shared__ __align__(16) char smem[21504];
    int t = threadIdx.x;
    int blk = blockIdx.x;

    if (blk >= 1280) {
        if (blk == 1472) {
            for (int i = t; i < 768; i += 256) {
                int l = i >> 7, k = i & 127;
                float a = dirs[l*384 + k];
                float b = dirs[l*384 + 128 + k];
                float c = dirs[l*384 + 256 + k];
                float nrm = sqrtf(a*a + b*b + c*c);
                float inv = 1.0f / fmaxf(nrm, 1e-12f);
                sdn[l*384 + k]       = a*inv;
                sdn[l*384 + 128 + k] = b*inv;
                sdn[l*384 + 256 + k] = c*inv;
            }
        } else {
            stp[(blk - 1280)*256 + t] = 0.0f;     // 192 blocks x 256 = 49152
        }
        return;
    }
    if (blk >= 512) {
        int g = blk - 512;
        int s = g >> 8, rb = g & 255;
        int wi = (s==0) ? 0 : (s==1) ? 1 : 3;
        do_gemm(x, (const float*)0, (const float*)0, (const float*)0,
                convW + wi*32768, convB + wi*256, fo + s*524288, rb, smem);
        return;
    }

    // ---------------- knn: one wave per vertex ----------------
    float* xs  = (float*)smem;
    float* ys  = xs + 1024;
    float* zs  = ys + 1024;
    float* sqs = zs + 1024;
    unsigned int* histBase = (unsigned int*)(smem + 16384);
    unsigned int* selBase  = (unsigned int*)(smem + 20480);

    int w = t >> 6, l = t & 63;
    int vglob = blk*4 + w;
    int b = vglob >> 10;
    int v = vglob & 1023;
    unsigned long long* keys = (unsigned long long*)smem + w*256;  // alias xs/ys
    unsigned int* hist = histBase + w*256;
    unsigned int* sel  = selBase + w*4;

    const float* vb = verts + b * 3072;
    for (int i = t; i < 1024; i += 256) {
        float xx = vb[i*3+0], yy = vb[i*3+1], zz = vb[i*3+2];
        xs[i] = xx; ys[i] = yy; zs[i] = zz;
        sqs[i] = xx*xx + yy*yy + zz*zz;
    }
    __syncthreads();

    float cx = xs[v], cy = ys[v], cz = zs[v], csq = sqs[v];
    unsigned long long K16[16];
    #pragma unroll
    for (int q = 0; q < 16; ++q) {
        int j = q*64 + l;
        float dot = cx*xs[j] + cy*ys[j] + cz*zs[j];
        float d = -2.0f*dot + csq + sqs[j];
        unsigned int u = __float_as_uint(d);
        u = (u & 0x80000000u) ? ~u : (u | 0x80000000u);
        K16[q] = (((unsigned long long)u) << 32) | (unsigned long long)j;
    }
    #pragma unroll
    for (int i = 0; i < 4; ++i) hist[l*4 + i] = 0u;
    __syncthreads();

    #pragma unroll
    for (int q = 0; q < 16; ++q)
        atomicAdd(&hist[(unsigned int)(K16[q] >> 56)], 1u);
    __syncthreads();

    {
        unsigned int h0 = hist[l*4], h1 = hist[l*4+1], h2 = hist[l*4+2], h3 = hist[l*4+3];
        unsigned int c1 = h0, c2 = h0+h1, c3 = h0+h1+h2, T = c3+h3;
        unsigned int xacc = T;
        #pragma unroll
        for (int off = 1; off < 64; off <<= 1) {
            unsigned int y = __shfl_up(xacc, off, 64);
            if (l >= off) xacc += y;
        }
        unsigned int P = xacc - T;
        unsigned int ex[4] = {P, P+c1, P+c2, P+c3};
        unsigned int hh[4] = {h0, h1, h2, h3};
        #pragma unroll
        for (int i = 0; i < 4; ++i) {
            if (ex[i] < 101u && ex[i] + hh[i] >= 101u) {
                sel[0] = (unsigned int)(l*4 + i);
                sel[1] = 101u - ex[i];
            }
        }
    }
    __syncthreads();
    unsigned int P8 = sel[0], rank2 = sel[1];
    #pragma unroll
    for (int i = 0; i < 4; ++i) hist[l*4 + i] = 0u;
    __syncthreads();

    #pragma unroll
    for (int q = 0; q < 16; ++q)
        if ((unsigned int)(K16[q] >> 56) == P8)
            atomicAdd(&hist[(unsigned int)(K16[q] >> 48) & 0xFFu], 1u);
    __syncthreads();

    {
        unsigned int h0 = hist[l*4], h1 = hist[l*4+1], h2 = hist[l*4+2], h3 = hist[l*4+3];
        unsigned int c1 = h0, c2 = h0+h1, c3 = h0+h1+h2, T = c3+h3;
        unsigned int xacc = T;
        #pragma unroll
        for (int off = 1; off < 64; off <<= 1) {
            unsigned int y = __shfl_up(xacc, off, 64);
            if (l >= off) xacc += y;
        }
        unsigned int P = xacc - T;
        unsigned int ex[4] = {P, P+c1, P+c2, P+c3};
        unsigned int hh[4] = {h0, h1, h2, h3};
        #pragma unroll
        for (int i = 0; i < 4; ++i) {
            if (ex[i] < rank2 && ex[i] + hh[i] >= rank2) {
                sel[2] = (P8 << 8) | (unsigned int)(l*4 + i);
                sel[3] = 0u;
            }
        }
    }
    __syncthreads();
    unsigned int P16 = sel[2];

    #pragma unroll
    for (int q = 0; q < 16; ++q) {
        if ((unsigned int)(K16[q] >> 48) <= P16) {
            unsigned int pos = atomicAdd(&sel[3], 1u);
            if (pos < 256u) keys[pos] = K16[q];
        }
    }
    __syncthreads();
    unsigned int cnt = sel[3];

    unsigned long long K[4];
    #pragma unroll
    for (int q = 0; q < 4; ++q) {
        unsigned int e = (unsigned int)(l*4 + q);
        K[q] = (e < cnt) ? keys[e] : 0xFFFFFFFFFFFFFFFFULL;
    }

    auto cswap = [&](int qa, int qb, int k) {
        int e = (l << 2) + qa;
        bool up = ((e & k) == 0);
        unsigned long long a = K[qa], bb2 = K[qb];
        unsigned long long mn = a < bb2 ? a : bb2;
        unsigned long long mx = a < bb2 ? bb2 : a;
        K[qa] = up ? mn : mx;
        K[qb] = up ? mx : mn;
    };
    #pragma unroll
    for (int k = 2; k <= 256; k <<= 1) {
        for (int j = k >> 1; j >= 4; j >>= 1) {
            int lj = j >> 2;
            #pragma unroll
            for (int q = 0; q < 4; ++q) {
                unsigned long long other = __shfl_xor(K[q], lj, 64);
                int e = (l << 2) + q;
                bool up = ((e & k) == 0);
                bool lower = ((l & lj) == 0);
                bool takeMin = (lower == up);
                unsigned long long mn = K[q] < other ? K[q] : other;
                unsigned long long mx = K[q] < other ? other : K[q];
                K[q] = takeMin ? mn : mx;
            }
        }
        if (k >= 4) { cswap(0, 2, k); cswap(1, 3, k); }
        cswap(0, 1, k); cswap(2, 3, k);
    }

    #pragma unroll
    for (int q = 0; q < 4; ++q) {
        int e = l*4 + q;
        if (e >= 1 && e <= 100)
            idxout[vglob*100 + (e-1)] = (int)(K[q] & 0xFFFFFFFFu);
    }
}

// ---------------------------------------------------------------------------
// Fallback standalone agg (r2-verified): grid (1024, nslots), 256 thr.
// ---------------------------------------------------------------------------
__global__ void agg_kernel(const int* __restrict__ idx, const float* __restrict__ verts,
                           const float* __restrict__ sdn, const float* __restrict__ fo,
                           int n0, int n1, int n2, int d0, int d1, int d2,
                           float* o0, float* o1, float* o2,
                           float* s0p, float* s1p, float* s2p)
{
    __shared__ __align__(16) char smem[4096];
    int slot = blockIdx.y;
    int n  = slot==0 ? n0 : slot==1 ? n1 : n2;
    int dI = slot==0 ? d0 : slot==1 ? d1 : d2;
    float* outp = slot==0 ? o0 : slot==1 ? o1 : o2;
    float* stp  = slot==0 ? s0p : slot==1 ? s1p : s2p;
    agg_unit(idx, verts, sdn, fo + slot*524288, n, dI, outp, stp,
             blockIdx.x, smem);
}

// ---------------------------------------------------------------------------
// Fallback standalone gemm (big-chunk body), up to 2 slots via blockIdx.y.
// ---------------------------------------------------------------------------
__global__ void gemm2_kernel(
    const float* inA, const float* stA, const float* gA, const float* beA,
    const float* WA, const float* biA, float* foA,
    const float* inB, const float* stB, const float* gB, const float* beB,
    const float* WB, const float* biB, float* foB)
{
    __shared__ __align__(16) char smem[70656];
    if (blockIdx.y == 0)
        do_gemm_big(inA, stA, gA, beA, WA, biA, foA, blockIdx.x, smem);
    else
        do_gemm_big(inB, stB, gB, beB, WB, biB, foB, blockIdx.x, smem);
}

// ---------------------------------------------------------------------------
// Mega kernel: K2..K6 fused, 512 blocks x 256 thr (2 blocks/CU — safe
// co-residency margin), grid.sync + explicit agent fences between phases.
//   P1 aggA  : 3072 units (6/block)   p0,p1,p3  <- fo slots 0,1,2
//   P2 gemmB :  512 units (1/block)   fo0 <- bn(p1)@W2 ; fo1 <- bn(p3)@W4
//   P3 aggB  : 2048 units (4/block)   p2 <- fo0 ; p4 <- fo1
//   P4 gemmC :  256 units (bid<256)   fo0 <- bn(p4)@W3
//   P5 aggC  : 1024 units (2/block)   p5 <- fo0
// __threadfence() (agent scope -> cross-XCD L2 wb/inv) wraps each sync:
// within one kernel there is no inter-kernel cache flush, so plain stores
// from phase N must be explicitly published for phase N+1 readers.
// ---------------------------------------------------------------------------
__global__ void __launch_bounds__(256, 2) mega_kernel(
    const int* __restrict__ idx, const float* __restrict__ verts,
    const float* __restrict__ sdn, float* __restrict__ fo,
    const float* __restrict__ convW, const float* __restrict__ convB,
    const float* __restrict__ gam, const float* __restrict__ bet,
    float* __restrict__ stp, float* __restrict__ pb)
{
    __shared__ __align__(16) char smem[21504];
    cg::grid_group grid = cg::this_grid();
    int bid = blockIdx.x;

    // P1: aggA (slots: n/dirs = 5/0 ->p0, 20/1 ->p1, 100/3 ->p3)
    for (int u = bid; u < 3072; u += 512) {
        int slot = u >> 10, xb = u & 1023;
        int n  = slot==0 ? 5 : slot==1 ? 20 : 100;
        int dI = slot==0 ? 0 : slot==1 ? 1 : 3;
        agg_unit(idx, verts, sdn, fo + slot*524288, n, dI,
                 pb + dI*262144, stp + dI*8192, xb, smem);
    }
    __threadfence(); grid.sync(); __threadfence();

    // P2: gemmB
    {
        int s = bid >> 8, rb = bid & 255;
        if (s == 0)
            do_gemm(pb + 262144, stp + 8192, gam + 128, bet + 128,
                    convW + 65536, convB + 512, fo, rb, smem);
        else
            do_gemm(pb + 3*262144, stp + 3*8192, gam + 384, bet + 384,
                    convW + 131072, convB + 1024, fo + 524288, rb, smem);
    }
    __threadfence(); grid.sync(); __threadfence();

    // P3: aggB (slots: 20/2 ->p2 <- fo0, 100/4 ->p4 <- fo1)
    for (int u = bid; u < 2048; u += 512) {
        int slot = u >> 10, xb = u & 1023;
        int n  = slot==0 ? 20 : 100;
        int dI = slot==0 ? 2 : 4;
        agg_unit(idx, verts, sdn, fo + slot*524288, n, dI,
                 pb + dI*262144, stp + dI*8192, xb, smem);
    }
    __threadfence(); grid.sync(); __threadfence();

    // P4: gemmC
    if (bid < 256)
        do_gemm(pb + 4*262144, stp + 4*8192, gam + 512, bet + 512,
                convW + 98304, convB + 768, fo, bid, smem);
    __threadfence(); grid.sync(); __threadfence();

    // P5: aggC (n=100, dirs 3, out/st index 5)
    for (int u = bid; u < 1024; u += 512)
        agg_unit(idx, verts, sdn, fo, 100, 3,
                 pb + 5*262144, stp + 5*8192, u, smem);
}

// ---------------------------------------------------------------------------
// Down-proj: [bn(p0)|bn(p1)|bn(p2)] (384) @ dW + db, relu.
// 16 rows x 128 cols per block, grid (128,2) = 256 blocks. 3 k128 chunks.
// ---------------------------------------------------------------------------
__global__ void down_kernel(
    const float* __restrict__ p0, const float* __restrict__ s0p,
    const float* __restrict__ g0, const float* __restrict__ be0,
    const float* __restrict__ p1, const float* __restrict__ s1p,
    const float* __restrict__ g1, const float* __restrict__ be1,
    const float* __restrict__ p2, const float* __restrict__ s2p,
    const float* __restrict__ g2, const float* __restrict__ be2,
    const float* __restrict__ dW, const float* __restrict__ db,
    float* __restrict__ out)
{
    __shared__ __align__(16) float rows[16*384];      // 24 KB
    __shared__ __align__(16) float4 wch4[4096];       // 64 KB  [k=128][cb=32]
    __shared__ float scale[384], shift[384];
    int t = threadIdx.x;
    int r0 = blockIdx.x * 16;
    int colblk = blockIdx.y;                          // 0 or 1

    for (int c = t; c < 384; c += 256) {
        int seg = c >> 7, cc = c & 127;
        const float* stp = seg==0 ? s0p : seg==1 ? s1p : s2p;
        const float* g   = seg==0 ? g0  : seg==1 ? g1  : g2;
        const float* be  = seg==0 ? be0 : seg==1 ? be1 : be2;
        float sm = 0.0f, sq = 0.0f;
        #pragma unroll 8
        for (int bk = 0; bk < 32; ++bk) {
            sm += stp[bk*256 + cc];
            sq += stp[bk*256 + 128 + cc];
        }
        float mu  = sm * (1.0f/2048.0f);
        float var = sq * (1.0f/2048.0f) - mu*mu;
        float s = rsqrtf(var + 1e-5f) * g[cc];
        scale[c] = s;
        shift[c] = be[cc] - mu*s;
    }
    __syncthreads();
    // stage 16 rows x 384 (bn-relu applied): 1536 float4, 6 per thread
    for (int q = t; q < 1536; q += 256) {
        int row = q / 96, rem = q - row*96;
        int c4 = rem << 2;
        int seg = c4 >> 7, cc = c4 & 127;
        const float* ps = seg==0 ? p0 : seg==1 ? p1 : p2;
        float4 v = *(const float4*)(ps + (r0+row)*128 + cc);
        v.x = fmaxf(v.x*scale[c4  ] + shift[c4  ], 0.0f);
        v.y = fmaxf(v.y*scale[c4+1] + shift[c4+1], 0.0f);
        v.z = fmaxf(v.z*scale[c4+2] + shift[c4+2], 0.0f);
        v.w = fmaxf(v.w*scale[c4+3] + shift[c4+3], 0.0f);
        *(float4*)&rows[row*384 + c4] = v;
    }

    int cb = t & 31;
    int rg = t >> 5;
    const float* a0r = rows + (rg*2)*384;
    const float* a1r = a0r + 384;
    const float4* W4 = (const float4*)dW;             // [384][64] f4
    float4 acc0 = make_float4(0.f,0.f,0.f,0.f);
    float4 acc1 = make_float4(0.f,0.f,0.f,0.f);
    for (int c = 0; c < 3; ++c) {
        __syncthreads();   // rows staged (c=0) / chunk c-1 fully consumed
        #pragma unroll
        for (int i = 0; i < 16; ++i) {
            int e = t + 256*i;                        // 0..4095
            wch4[e] = W4[c*8192 + colblk*32 + (e >> 5)*64 + (e & 31)];
        }
        __syncthreads();
        int kb = c*128;
        #pragma unroll 8
        for (int k = 0; k < 128; k += 4) {
            float4 a0 = *(const float4*)(a0r + kb + k);
            float4 a1 = *(const float4*)(a1r + kb + k);
            float4 w;
            w = wch4[(k+0)*32+cb];
            acc0.x += a0.x*w.x; acc0.y += a0.x*w.y; acc0.z += a0.x*w.z; acc0.w += a0.x*w.w;
            acc1.x += a1.x*w.x; acc1.y += a1.x*w.y; acc1.z += a1.x*w.z; acc1.w += a1.x*w.w;
            w = wch4[(k+1)*32+cb];
            acc0.x += a0.y*w.x; acc0.y += a0.y*w.y; acc0.z += a0.y*w.z; acc0.w += a0.y*w.w;
            acc1.x += a1.y*w.x; acc1.y += a1.y*w.y; acc1.z += a1.y*w.z; acc1.w += a1.y*w.w;
            w = wch4[(k+2)*32+cb];
            acc0.x += a0.z*w.x; acc0.y += a0.z*w.y; acc0.z += a0.z*w.z; acc0.w += a0.z*w.w;
            acc1.x += a1.z*w.x; acc1.y += a1.z*w.y; acc1.z += a1.z*w.z; acc1.w += a1.z*w.w;
            w = wch4[(k+3)*32+cb];
            acc0.x += a0.w*w.x; acc0.y += a0.w*w.y; acc0.z += a0.w*w.z; acc0.w += a0.w*w.w;
            acc1.x += a1.w*w.x; acc1.y += a1.w*w.y; acc1.z += a1.w*w.z; acc1.w += a1.w*w.w;
        }
    }
    float4 b4 = ((const float4*)db)[colblk*32 + cb];
    float4 o0, o1;
    o0.x = fmaxf(acc0.x + b4.x, 0.0f); o0.y = fmaxf(acc0.y + b4.y, 0.0f);
    o0.z = fmaxf(acc0.z + b4.z, 0.0f); o0.w = fmaxf(acc0.w + b4.w, 0.0f);
    o1.x = fmaxf(acc1.x + b4.x, 0.0f); o1.y = fmaxf(acc1.y + b4.y, 0.0f);
    o1.z = fmaxf(acc1.z + b4.z, 0.0f); o1.w = fmaxf(acc1.w + b4.w, 0.0f);
    ((float4*)out)[(r0 + rg*2    )*64 + colblk*32 + cb] = o0;
    ((float4*)out)[(r0 + rg*2 + 1)*64 + colblk*32 + cb] = o1;
}

// ---------------------------------------------------------------------------
extern "C" void kernel_launch(void* const* d_in, const int* in_sizes, int n_in,
                              void* d_out, int out_size, void* d_ws, size_t ws_size,
                              hipStream_t stream)
{
    (void)in_sizes; (void)n_in; (void)out_size; (void)ws_size;
    const float* verts = (const float*)d_in[0];
    const float* x     = (const float*)d_in[1];
    const float* convW = (const float*)d_in[2];
    const float* convB = (const float*)d_in[3];
    const float* dirs  = (const float*)d_in[4];
    const float* gam   = (const float*)d_in[5];
    const float* bet   = (const float*)d_in[6];
    const float* dW    = (const float*)d_in[7];
    const float* db    = (const float*)d_in[8];
    float* out = (float*)d_out;

    char* ws = (char*)d_ws;
    int*   idxb = (int*)(ws);
    float* sdn  = (float*)(ws + 819200);
    float* stp  = (float*)(ws + 828416);         // 6 x 32 x 256 f32
    float* fo   = (float*)(ws + 1025024);        // 3 x (2048,256)
    float* pb   = (float*)(ws + 7316480);        // p_k = pb + k*262144

    float* p0 = pb,            *p1 = pb + 262144,   *p2 = pb + 2*262144;
    float* p3 = pb + 3*262144, *p4 = pb + 4*262144, *p5 = pb + 5*262144;
    float* stL0 = stp,         *stL1 = stp + 8192,  *stL2 = stp + 16384;
    float* stL3 = stp + 24576, *stL4 = stp + 32768, *stL5 = stp + 40960;
    const float* nf = (const float*)0;
    float* nw = (float*)0;

    // K1: knn + gemmA (L0,L1,L3 from x) + zero stp + dirs norm
    k1_kernel<<<1473, 256, 0, stream>>>(verts, dirs, x, convW, convB,
                                        idxb, sdn, stp, fo);

    // MEGA: aggA | gemmB | aggB | gemmC | aggC (cooperative; fallback to
    // the verified r2 multi-launch sequence if the enqueue is rejected).
    void* kargs[] = {
        (void*)&idxb, (void*)&verts, (void*)&sdn, (void*)&fo,
        (void*)&convW, (void*)&convB, (void*)&gam, (void*)&bet,
        (void*)&stp, (void*)&pb
    };
    hipError_t cerr = hipLaunchCooperativeKernel(
        (void*)mega_kernel, dim3(512), dim3(256), kargs, 0, stream);
    if (cerr != hipSuccess) {
        // r2-verified fallback path
        agg_kernel<<<dim3(1024,3), 256, 0, stream>>>(
            idxb, verts, sdn, fo, 5, 20, 100, 0, 1, 3,
            p0, p1, p3, stL0, stL1, stL3);
        gemm2_kernel<<<dim3(256,2), 256, 0, stream>>>(
            p1, stL1, gam + 128, bet + 128, convW + 65536,  convB + 512,  fo,
            p3, stL3, gam + 384, bet + 384, convW + 131072, convB + 1024, fo + 524288);
        agg_kernel<<<dim3(1024,2), 256, 0, stream>>>(
            idxb, verts, sdn, fo, 20, 100, 0, 2, 4, 0,
            p2, p4, nw, stL2, stL4, nw);
        gemm2_kernel<<<dim3(256,1), 256, 0, stream>>>(
            p4, stL4, gam + 512, bet + 512, convW + 98304, convB + 768, fo,
            nf, nf, nf, nf, nf, nf, nw);
        agg_kernel<<<dim3(1024,1), 256, 0, stream>>>(
            idxb, verts, sdn, fo, 100, 0, 0, 3, 0, 0,
            p5, nw, nw, stL5, nw, nw);
    }

    // DOWN: bn(p0,stL0,g0,b0) | bn(p2,stL2,g2,b2) | bn(p5,stL5,g3,b3)
    down_kernel<<<dim3(128,2), 256, 0, stream>>>(
        p0, stL0, gam, bet,
        p2, stL2, gam + 256, bet + 256,
        p5, stL5, gam + 384, bet + 384,
        dW, db, out);
}

// Round 6
// 175.623 us; speedup vs baseline: 4.1885x; 4.1885x over previous
//
#include <hip/hip_runtime.h>

// ---------------------------------------------------------------------------
// Workspace:
//   idxb 0        : (2048,100) int       819200
//   sdn  819200   : (6,3,128)              9216
//   stp  828416   : 6 layers x 32 banks x 256 f32  196608   (BN partials)
//   fo   1025024  : 3 x (2048,256)       6291456
//   p0.. 7316480  : 6 x (2048,128)       6291456
// r6: r2-verified bodies; schedule re-plumb only. p0-agg (n=5, needed only
// by down) moved K2 -> K6 so K2 is a single scheduling pass (2048 blocks);
// n=100 slot is y=0 everywhere (dispatches first). fo lifetime re-plumb:
//   K1 gemmA: L0->fo0, L1->fo1, L3->fo2       (fo0 preserved until K6!)
//   K2 agg:   p3<-fo2(n100,d3), p1<-fo1(n20,d1)
//   K3 gemm:  L2=bn(p1)@W2 -> fo2 ; L4=bn(p3)@W4 -> fo1
//   K4 agg:   p4<-fo1(n100,d4), p2<-fo2(n20,d2)
//   K5 gemm:  L5=bn(p4)@W3 -> fo1
//   K6 agg:   p5<-fo1(n100,d3), p0<-fo0(n5,d0)
//   K7 down:  bn(p0)|bn(p2)|bn(p5) @ dW
// [r5 lesson: cooperative fusion = 620us (per-thread agent fences + HBM-spin
//  grid.sync ~140us/boundary). Multi-launch is the right structure.]
// ---------------------------------------------------------------------------

// ---------------------------------------------------------------------------
// GEMM body (chunked-LDS W, 16KB chunks): used only inside k1 (LDS capped
// at 21.5KB so knn blocks keep ~7 blocks/CU; gemm latency hidden by
// co-resident knn blocks). [r1 lesson: no reg-prefetch across barriers]
// ---------------------------------------------------------------------------
__device__ __forceinline__ void do_gemm(
    const float* __restrict__ in, const float* __restrict__ stp,
    const float* __restrict__ gm, const float* __restrict__ bt,
    const float* __restrict__ W, const float* __restrict__ bi,
    float* __restrict__ out, int rb, char* smemc)
{
    float* rows  = (float*)smemc;           // 1024 floats
    float* wch   = rows + 1024;             // 4096 floats (16 KB)
    float* scale = wch + 4096;              // 128
    float* shift = scale + 128;             // 128
    int t = threadIdx.x;
    if (t < 128) {
        float sc = 1.0f, sf = 0.0f;
        if (stp) {
            float sm = 0.0f, sq = 0.0f;
            #pragma unroll 8
            for (int bk = 0; bk < 32; ++bk) {
                sm += stp[bk*256 + t];
                sq += stp[bk*256 + 128 + t];
            }
            float mu  = sm * (1.0f/2048.0f);
            float var = sq * (1.0f/2048.0f) - mu*mu;
            sc = rsqrtf(var + 1e-5f) * gm[t];
            sf = bt[t] - mu*sc;
        }
        scale[t] = sc; shift[t] = sf;
    }
    __syncthreads();
    int r0 = rb * 8;
    {
        float4 v = ((const float4*)(in + r0*128))[t];
        if (stp) {
            int c4 = (t & 31) << 2;
            v.x = fmaxf(v.x*scale[c4  ] + shift[c4  ], 0.0f);
            v.y = fmaxf(v.y*scale[c4+1] + shift[c4+1], 0.0f);
            v.z = fmaxf(v.z*scale[c4+2] + shift[c4+2], 0.0f);
            v.w = fmaxf(v.w*scale[c4+3] + shift[c4+3], 0.0f);
        }
        ((float4*)rows)[t] = v;
    }
    int cb = t & 63, rp = (t >> 6) << 1;
    const float* a0r = rows + rp*128;
    const float* a1r = a0r + 128;
    const float4* W4 = (const float4*)W;
    float4* wch4 = (float4*)wch;
    float4 acc0 = make_float4(0.f,0.f,0.f,0.f);
    float4 acc1 = make_float4(0.f,0.f,0.f,0.f);
    for (int c = 0; c < 8; ++c) {
        __syncthreads();
        #pragma unroll
        for (int i = 0; i < 4; ++i)
            wch4[t + 256*i] = W4[c*1024 + t + 256*i];
        __syncthreads();
        int kb = c*16;
        #pragma unroll
        for (int k = 0; k < 16; k += 4) {
            float4 a0 = *(const float4*)(a0r + kb + k);
            float4 a1 = *(const float4*)(a1r + kb + k);
            float4 w;
            w = wch4[(k+0)*64+cb];
            acc0.x += a0.x*w.x; acc0.y += a0.x*w.y; acc0.z += a0.x*w.z; acc0.w += a0.x*w.w;
            acc1.x += a1.x*w.x; acc1.y += a1.x*w.y; acc1.z += a1.x*w.z; acc1.w += a1.x*w.w;
            w = wch4[(k+1)*64+cb];
            acc0.x += a0.y*w.x; acc0.y += a0.y*w.y; acc0.z += a0.y*w.z; acc0.w += a0.y*w.w;
            acc1.x += a1.y*w.x; acc1.y += a1.y*w.y; acc1.z += a1.y*w.z; acc1.w += a1.y*w.w;
            w = wch4[(k+2)*64+cb];
            acc0.x += a0.z*w.x; acc0.y += a0.z*w.y; acc0.z += a0.z*w.z; acc0.w += a0.z*w.w;
            acc1.x += a1.z*w.x; acc1.y += a1.z*w.y; acc1.z += a1.z*w.z; acc1.w += a1.z*w.w;
            w = wch4[(k+3)*64+cb];
            acc0.x += a0.w*w.x; acc0.y += a0.w*w.y; acc0.z += a0.w*w.z; acc0.w += a0.w*w.w;
            acc1.x += a1.w*w.x; acc1.y += a1.w*w.y; acc1.z += a1.w*w.z; acc1.w += a1.w*w.w;
        }
    }
    float4 b4 = ((const float4*)bi)[cb];
    acc0.x += b4.x; acc0.y += b4.y; acc0.z += b4.z; acc0.w += b4.w;
    acc1.x += b4.x; acc1.y += b4.y; acc1.z += b4.z; acc1.w += b4.w;
    ((float4*)out)[(r0+rp  )*64 + cb] = acc0;
    ((float4*)out)[(r0+rp+1)*64 + cb] = acc1;
}

// ---------------------------------------------------------------------------
// Big-chunk GEMM body (K3/K5): chunk = k64 (64KB), 2 chunks -> 4x fewer
// exposed load-latency boundaries. LDS 69KB; 2 blocks/CU for K3.
// ---------------------------------------------------------------------------
__device__ __forceinline__ void do_gemm_big(
    const float* __restrict__ in, const float* __restrict__ stp,
    const float* __restrict__ gm, const float* __restrict__ bt,
    const float* __restrict__ W, const float* __restrict__ bi,
    float* __restrict__ out, int rb, char* smemc)
{
    float* rows  = (float*)smemc;           // 1024 floats
    float* wch   = rows + 1024;             // 16384 floats (64 KB)
    float* scale = wch + 16384;             // 128
    float* shift = scale + 128;             // 128
    int t = threadIdx.x;
    if (t < 128) {
        float sc = 1.0f, sf = 0.0f;
        if (stp) {
            float sm = 0.0f, sq = 0.0f;
            #pragma unroll 8
            for (int bk = 0; bk < 32; ++bk) {
                sm += stp[bk*256 + t];
                sq += stp[bk*256 + 128 + t];
            }
            float mu  = sm * (1.0f/2048.0f);
            float var = sq * (1.0f/2048.0f) - mu*mu;
            sc = rsqrtf(var + 1e-5f) * gm[t];
            sf = bt[t] - mu*sc;
        }
        scale[t] = sc; shift[t] = sf;
    }
    __syncthreads();
    int r0 = rb * 8;
    {
        float4 v = ((const float4*)(in + r0*128))[t];
        if (stp) {
            int c4 = (t & 31) << 2;
            v.x = fmaxf(v.x*scale[c4  ] + shift[c4  ], 0.0f);
            v.y = fmaxf(v.y*scale[c4+1] + shift[c4+1], 0.0f);
            v.z = fmaxf(v.z*scale[c4+2] + shift[c4+2], 0.0f);
            v.w = fmaxf(v.w*scale[c4+3] + shift[c4+3], 0.0f);
        }
        ((float4*)rows)[t] = v;
    }
    int cb = t & 63, rp = (t >> 6) << 1;
    const float* a0r = rows + rp*128;
    const float* a1r = a0r + 128;
    const float4* W4 = (const float4*)W;   // [128][64] f4
    float4* wch4 = (float4*)wch;           // [64][64] f4 per chunk
    float4 acc0 = make_float4(0.f,0.f,0.f,0.f);
    float4 acc1 = make_float4(0.f,0.f,0.f,0.f);
    for (int c = 0; c < 2; ++c) {
        __syncthreads();
        #pragma unroll
        for (int i = 0; i < 16; ++i)
            wch4[t + 256*i] = W4[c*4096 + t + 256*i];
        __syncthreads();
        int kb = c*64;
        #pragma unroll 4
        for (int k = 0; k < 64; k += 4) {
            float4 a0 = *(const float4*)(a0r + kb + k);
            float4 a1 = *(const float4*)(a1r + kb + k);
            float4 w;
            w = wch4[(k+0)*64+cb];
            acc0.x += a0.x*w.x; acc0.y += a0.x*w.y; acc0.z += a0.x*w.z; acc0.w += a0.x*w.w;
            acc1.x += a1.x*w.x; acc1.y += a1.x*w.y; acc1.z += a1.x*w.z; acc1.w += a1.x*w.w;
            w = wch4[(k+1)*64+cb];
            acc0.x += a0.y*w.x; acc0.y += a0.y*w.y; acc0.z += a0.y*w.z; acc0.w += a0.y*w.w;
            acc1.x += a1.y*w.x; acc1.y += a1.y*w.y; acc1.z += a1.y*w.z; acc1.w += a1.y*w.w;
            w = wch4[(k+2)*64+cb];
            acc0.x += a0.z*w.x; acc0.y += a0.z*w.y; acc0.z += a0.z*w.z; acc0.w += a0.z*w.w;
            acc1.x += a1.z*w.x; acc1.y += a1.z*w.y; acc1.z += a1.z*w.z; acc1.w += a1.z*w.w;
            w = wch4[(k+3)*64+cb];
            acc0.x += a0.w*w.x; acc0.y += a0.w*w.y; acc0.z += a0.w*w.z; acc0.w += a0.w*w.w;
            acc1.x += a1.w*w.x; acc1.y += a1.w*w.y; acc1.z += a1.w*w.z; acc1.w += a1.w*w.w;
        }
    }
    float4 b4 = ((const float4*)bi)[cb];
    acc0.x += b4.x; acc0.y += b4.y; acc0.z += b4.z; acc0.w += b4.w;
    acc1.x += b4.x; acc1.y += b4.y; acc1.z += b4.z; acc1.w += b4.w;
    ((float4*)out)[(r0+rp  )*64 + cb] = acc0;
    ((float4*)out)[(r0+rp+1)*64 + cb] = acc1;
}

// ---------------------------------------------------------------------------
// K1: wave-sync knn (0..511) + gemmA (512..1279) + zero stp (1280..1471) +
// dirs norm (1472). knn algorithm verified r8-r12.
// ---------------------------------------------------------------------------
__global__ void k1_kernel(const float* __restrict__ verts, const float* __restrict__ dirs,
                          const float* __restrict__ x,
                          const float* __restrict__ convW, const float* __restrict__ convB,
                          int* __restrict__ idxout, float* __restrict__ sdn,
                          float* __restrict__ stp, float* __restrict__ fo)
{
    __shared__ __align__(16) char smem[21504];
    int t = threadIdx.x;
    int blk = blockIdx.x;

    if (blk >= 1280) {
        if (blk == 1472) {
            for (int i = t; i < 768; i += 256) {
                int l = i >> 7, k = i & 127;
                float a = dirs[l*384 + k];
                float b = dirs[l*384 + 128 + k];
                float c = dirs[l*384 + 256 + k];
                float nrm = sqrtf(a*a + b*b + c*c);
                float inv = 1.0f / fmaxf(nrm, 1e-12f);
                sdn[l*384 + k]       = a*inv;
                sdn[l*384 + 128 + k] = b*inv;
                sdn[l*384 + 256 + k] = c*inv;
            }
        } else {
            stp[(blk - 1280)*256 + t] = 0.0f;     // 192 blocks x 256 = 49152
        }
        return;
    }
    if (blk >= 512) {
        int g = blk - 512;
        int s = g >> 8, rb = g & 255;
        int wi = (s==0) ? 0 : (s==1) ? 1 : 3;
        do_gemm(x, (const float*)0, (const float*)0, (const float*)0,
                convW + wi*32768, convB + wi*256, fo + s*524288, rb, smem);
        return;
    }

    // ---------------- knn: one wave per vertex ----------------
    float* xs  = (float*)smem;
    float* ys  = xs + 1024;
    float* zs  = ys + 1024;
    float* sqs = zs + 1024;
    unsigned int* histBase = (unsigned int*)(smem + 16384);
    unsigned int* selBase  = (unsigned int*)(smem + 20480);

    int w = t >> 6, l = t & 63;
    int vglob = blk*4 + w;
    int b = vglob >> 10;
    int v = vglob & 1023;
    unsigned long long* keys = (unsigned long long*)smem + w*256;  // alias xs/ys
    unsigned int* hist = histBase + w*256;
    unsigned int* sel  = selBase + w*4;

    const float* vb = verts + b * 3072;
    for (int i = t; i < 1024; i += 256) {
        float xx = vb[i*3+0], yy = vb[i*3+1], zz = vb[i*3+2];
        xs[i] = xx; ys[i] = yy; zs[i] = zz;
        sqs[i] = xx*xx + yy*yy + zz*zz;
    }
    __syncthreads();

    float cx = xs[v], cy = ys[v], cz = zs[v], csq = sqs[v];
    unsigned long long K16[16];
    #pragma unroll
    for (int q = 0; q < 16; ++q) {
        int j = q*64 + l;
        float dot = cx*xs[j] + cy*ys[j] + cz*zs[j];
        float d = -2.0f*dot + csq + sqs[j];
        unsigned int u = __float_as_uint(d);
        u = (u & 0x80000000u) ? ~u : (u | 0x80000000u);
        K16[q] = (((unsigned long long)u) << 32) | (unsigned long long)j;
    }
    #pragma unroll
    for (int i = 0; i < 4; ++i) hist[l*4 + i] = 0u;
    __syncthreads();

    #pragma unroll
    for (int q = 0; q < 16; ++q)
        atomicAdd(&hist[(unsigned int)(K16[q] >> 56)], 1u);
    __syncthreads();

    {
        unsigned int h0 = hist[l*4], h1 = hist[l*4+1], h2 = hist[l*4+2], h3 = hist[l*4+3];
        unsigned int c1 = h0, c2 = h0+h1, c3 = h0+h1+h2, T = c3+h3;
        unsigned int xacc = T;
        #pragma unroll
        for (int off = 1; off < 64; off <<= 1) {
            unsigned int y = __shfl_up(xacc, off, 64);
            if (l >= off) xacc += y;
        }
        unsigned int P = xacc - T;
        unsigned int ex[4] = {P, P+c1, P+c2, P+c3};
        unsigned int hh[4] = {h0, h1, h2, h3};
        #pragma unroll
        for (int i = 0; i < 4; ++i) {
            if (ex[i] < 101u && ex[i] + hh[i] >= 101u) {
                sel[0] = (unsigned int)(l*4 + i);
                sel[1] = 101u - ex[i];
            }
        }
    }
    __syncthreads();
    unsigned int P8 = sel[0], rank2 = sel[1];
    #pragma unroll
    for (int i = 0; i < 4; ++i) hist[l*4 + i] = 0u;
    __syncthreads();

    #pragma unroll
    for (int q = 0; q < 16; ++q)
        if ((unsigned int)(K16[q] >> 56) == P8)
            atomicAdd(&hist[(unsigned int)(K16[q] >> 48) & 0xFFu], 1u);
    __syncthreads();

    {
        unsigned int h0 = hist[l*4], h1 = hist[l*4+1], h2 = hist[l*4+2], h3 = hist[l*4+3];
        unsigned int c1 = h0, c2 = h0+h1, c3 = h0+h1+h2, T = c3+h3;
        unsigned int xacc = T;
        #pragma unroll
        for (int off = 1; off < 64; off <<= 1) {
            unsigned int y = __shfl_up(xacc, off, 64);
            if (l >= off) xacc += y;
        }
        unsigned int P = xacc - T;
        unsigned int ex[4] = {P, P+c1, P+c2, P+c3};
        unsigned int hh[4] = {h0, h1, h2, h3};
        #pragma unroll
        for (int i = 0; i < 4; ++i) {
            if (ex[i] < rank2 && ex[i] + hh[i] >= rank2) {
                sel[2] = (P8 << 8) | (unsigned int)(l*4 + i);
                sel[3] = 0u;
            }
        }
    }
    __syncthreads();
    unsigned int P16 = sel[2];

    #pragma unroll
    for (int q = 0; q < 16; ++q) {
        if ((unsigned int)(K16[q] >> 48) <= P16) {
            unsigned int pos = atomicAdd(&sel[3], 1u);
            if (pos < 256u) keys[pos] = K16[q];
        }
    }
    __syncthreads();
    unsigned int cnt = sel[3];

    unsigned long long K[4];
    #pragma unroll
    for (int q = 0; q < 4; ++q) {
        unsigned int e = (unsigned int)(l*4 + q);
        K[q] = (e < cnt) ? keys[e] : 0xFFFFFFFFFFFFFFFFULL;
    }

    auto cswap = [&](int qa, int qb, int k) {
        int e = (l << 2) + qa;
        bool up = ((e & k) == 0);
        unsigned long long a = K[qa], bb2 = K[qb];
        unsigned long long mn = a < bb2 ? a : bb2;
        unsigned long long mx = a < bb2 ? bb2 : a;
        K[qa] = up ? mn : mx;
        K[qb] = up ? mx : mn;
    };
    #pragma unroll
    for (int k = 2; k <= 256; k <<= 1) {
        for (int j = k >> 1; j >= 4; j >>= 1) {
            int lj = j >> 2;
            #pragma unroll
            for (int q = 0; q < 4; ++q) {
                unsigned long long other = __shfl_xor(K[q], lj, 64);
                int e = (l << 2) + q;
                bool up = ((e & k) == 0);
                bool lower = ((l & lj) == 0);
                bool takeMin = (lower == up);
                unsigned long long mn = K[q] < other ? K[q] : other;
                unsigned long long mx = K[q] < other ? other : K[q];
                K[q] = takeMin ? mn : mx;
            }
        }
        if (k >= 4) { cswap(0, 2, k); cswap(1, 3, k); }
        cswap(0, 1, k); cswap(2, 3, k);
    }

    #pragma unroll
    for (int q = 0; q < 4; ++q) {
        int e = l*4 + q;
        if (e >= 1 && e <= 100)
            idxout[vglob*100 + (e-1)] = (int)(K[q] & 0xFFFFFFFFu);
    }
}

// ---------------------------------------------------------------------------
// Agg + fused BN-partials (r2-verified scalar body). grid (1024, nslots).
// Per-slot fo index f0/f1/f2 (fo slot re-plumb, r6). 256 thr = 2 rows.
// ---------------------------------------------------------------------------
__global__ void agg_kernel(const int* __restrict__ idx, const float* __restrict__ verts,
                           const float* __restrict__ sdn, const float* __restrict__ fo,
                           int n0, int n1, int n2, int d0, int d1, int d2,
                           int f0, int f1, int f2,
                           float* o0, float* o1, float* o2,
                           float* s0p, float* s1p, float* s2p)
{
    __shared__ float4 ds4s[200];
    __shared__ int jss[200];
    int slot = blockIdx.y;
    int n  = slot==0 ? n0 : slot==1 ? n1 : n2;
    int dI = slot==0 ? d0 : slot==1 ? d1 : d2;
    int fI = slot==0 ? f0 : slot==1 ? f1 : f2;
    float* outp = slot==0 ? o0 : slot==1 ? o1 : o2;
    float* stp  = slot==0 ? s0p : slot==1 ? s1p : s2p;
    const float* fos = fo + fI * 524288;
    const float* sd = sdn + dI * 384;

    int t = threadIdx.x;
    int h = t >> 7, tt = t & 127;
    float4* ds4 = ds4s + h*100;
    int* js = jss + h*100;
    int r = blockIdx.x*2 + h;
    int b = r >> 10;

    if (tt < n) {
        int j = idx[r*100 + tt];
        js[tt] = j;
        const float* pj = verts + (b*1024 + j)*3;
        const float* pv = verts + r*3;
        float dx = pj[0]-pv[0], dy = pj[1]-pv[1], dz = pj[2]-pv[2];
        float nm = sqrtf(dx*dx + dy*dy + dz*dz);
        float inv = 1.0f / fmaxf(nm, 1e-12f);
        ds4[tt] = make_float4(dx*inv, dy*inv, dz*inv, 0.0f);
    }
    __syncthreads();
    float s0 = sd[tt], s1 = sd[128+tt], s2 = sd[256+tt];
    int bb = b * 1024;
    float m = -3.0e38f;
    for (int q = 0; q < n; q += 5) {
        float th[5];
        const float* p[5];
        #pragma unroll
        for (int u = 0; u < 5; ++u) {
            float4 dq = ds4[q+u];
            th[u] = fmaxf(dq.x*s0 + dq.y*s1 + dq.z*s2, 0.0f);
            p[u] = fos + (size_t)(bb + js[q+u])*256 + 128 + tt;
        }
        float vv[5];
        #pragma unroll
        for (int u = 0; u < 5; ++u) vv[u] = *p[u];
        #pragma unroll
        for (int u = 0; u < 5; ++u) m = fmaxf(m, th[u]*vv[u]);
    }
    float val = fos[r*256 + tt] + m;
    outp[r*128 + tt] = val;
    float* bank = stp + (r & 31)*256;
    atomicAdd(&bank[tt], val);
    atomicAdd(&bank[128+tt], val*val);
}

// ---------------------------------------------------------------------------
// Standalone gemm (big-chunk body), up to 2 slots via blockIdx.y.
// grid (256, nslots), 256 thr. LDS 69KB -> 2 blocks/CU for K3.
// ---------------------------------------------------------------------------
__global__ void gemm2_kernel(
    const float* inA, const float* stA, const float* gA, const float* beA,
    const float* WA, const float* biA, float* foA,
    const float* inB, const float* stB, const float* gB, const float* beB,
    const float* WB, const float* biB, float* foB)
{
    __shared__ __align__(16) char smem[70656];
    if (blockIdx.y == 0)
        do_gemm_big(inA, stA, gA, beA, WA, biA, foA, blockIdx.x, smem);
    else
        do_gemm_big(inB, stB, gB, beB, WB, biB, foB, blockIdx.x, smem);
}

// ---------------------------------------------------------------------------
// Down-proj: [bn(p0)|bn(p1)|bn(p2)] (384) @ dW + db, relu.
// 16 rows x 128 cols per block, grid (128,2) = 256 blocks.
// W slice per block = 384x128 in 3 chunks of k=128 (64KB each). LDS 91KB.
// ---------------------------------------------------------------------------
__global__ void down_kernel(
    const float* __restrict__ p0, const float* __restrict__ s0p,
    const float* __restrict__ g0, const float* __restrict__ be0,
    const float* __restrict__ p1, const float* __restrict__ s1p,
    const float* __restrict__ g1, const float* __restrict__ be1,
    const float* __restrict__ p2, const float* __restrict__ s2p,
    const float* __restrict__ g2, const float* __restrict__ be2,
    const float* __restrict__ dW, const float* __restrict__ db,
    float* __restrict__ out)
{
    __shared__ __align__(16) float rows[16*384];      // 24 KB
    __shared__ __align__(16) float4 wch4[4096];       // 64 KB  [k=128][cb=32]
    __shared__ float scale[384], shift[384];
    int t = threadIdx.x;
    int r0 = blockIdx.x * 16;
    int colblk = blockIdx.y;                          // 0 or 1

    for (int c = t; c < 384; c += 256) {
        int seg = c >> 7, cc = c & 127;
        const float* stp = seg==0 ? s0p : seg==1 ? s1p : s2p;
        const float* g   = seg==0 ? g0  : seg==1 ? g1  : g2;
        const float* be  = seg==0 ? be0 : seg==1 ? be1 : be2;
        float sm = 0.0f, sq = 0.0f;
        #pragma unroll 8
        for (int bk = 0; bk < 32; ++bk) {
            sm += stp[bk*256 + cc];
            sq += stp[bk*256 + 128 + cc];
        }
        float mu  = sm * (1.0f/2048.0f);
        float var = sq * (1.0f/2048.0f) - mu*mu;
        float s = rsqrtf(var + 1e-5f) * g[cc];
        scale[c] = s;
        shift[c] = be[cc] - mu*s;
    }
    __syncthreads();
    // stage 16 rows x 384 (bn-relu applied): 1536 float4, 6 per thread
    for (int q = t; q < 1536; q += 256) {
        int row = q / 96, rem = q - row*96;
        int c4 = rem << 2;
        int seg = c4 >> 7, cc = c4 & 127;
        const float* ps = seg==0 ? p0 : seg==1 ? p1 : p2;
        float4 v = *(const float4*)(ps + (r0+row)*128 + cc);
        v.x = fmaxf(v.x*scale[c4  ] + shift[c4  ], 0.0f);
        v.y = fmaxf(v.y*scale[c4+1] + shift[c4+1], 0.0f);
        v.z = fmaxf(v.z*scale[c4+2] + shift[c4+2], 0.0f);
        v.w = fmaxf(v.w*scale[c4+3] + shift[c4+3], 0.0f);
        *(float4*)&rows[row*384 + c4] = v;
    }

    int cb = t & 31;
    int rg = t >> 5;
    const float* a0r = rows + (rg*2)*384;
    const float* a1r = a0r + 384;
    const float4* W4 = (const float4*)dW;             // [384][64] f4
    float4 acc0 = make_float4(0.f,0.f,0.f,0.f);
    float4 acc1 = make_float4(0.f,0.f,0.f,0.f);
    for (int c = 0; c < 3; ++c) {
        __syncthreads();   // rows staged (c=0) / chunk c-1 fully consumed
        #pragma unroll
        for (int i = 0; i < 16; ++i) {
            int e = t + 256*i;                        // 0..4095
            wch4[e] = W4[c*8192 + colblk*32 + (e >> 5)*64 + (e & 31)];
        }
        __syncthreads();
        int kb = c*128;
        #pragma unroll 8
        for (int k = 0; k < 128; k += 4) {
            float4 a0 = *(const float4*)(a0r + kb + k);
            float4 a1 = *(const float4*)(a1r + kb + k);
            float4 w;
            w = wch4[(k+0)*32+cb];
            acc0.x += a0.x*w.x; acc0.y += a0.x*w.y; acc0.z += a0.x*w.z; acc0.w += a0.x*w.w;
            acc1.x += a1.x*w.x; acc1.y += a1.x*w.y; acc1.z += a1.x*w.z; acc1.w += a1.x*w.w;
            w = wch4[(k+1)*32+cb];
            acc0.x += a0.y*w.x; acc0.y += a0.y*w.y; acc0.z += a0.y*w.z; acc0.w += a0.y*w.w;
            acc1.x += a1.y*w.x; acc1.y += a1.y*w.y; acc1.z += a1.y*w.z; acc1.w += a1.y*w.w;
            w = wch4[(k+2)*32+cb];
            acc0.x += a0.z*w.x; acc0.y += a0.z*w.y; acc0.z += a0.z*w.z; acc0.w += a0.z*w.w;
            acc1.x += a1.z*w.x; acc1.y += a1.z*w.y; acc1.z += a1.z*w.z; acc1.w += a1.z*w.w;
            w = wch4[(k+3)*32+cb];
            acc0.x += a0.w*w.x; acc0.y += a0.w*w.y; acc0.z += a0.w*w.z; acc0.w += a0.w*w.w;
            acc1.x += a1.w*w.x; acc1.y += a1.w*w.y; acc1.z += a1.w*w.z; acc1.w += a1.w*w.w;
        }
    }
    float4 b4 = ((const float4*)db)[colblk*32 + cb];
    float4 o0, o1;
    o0.x = fmaxf(acc0.x + b4.x, 0.0f); o0.y = fmaxf(acc0.y + b4.y, 0.0f);
    o0.z = fmaxf(acc0.z + b4.z, 0.0f); o0.w = fmaxf(acc0.w + b4.w, 0.0f);
    o1.x = fmaxf(acc1.x + b4.x, 0.0f); o1.y = fmaxf(acc1.y + b4.y, 0.0f);
    o1.z = fmaxf(acc1.z + b4.z, 0.0f); o1.w = fmaxf(acc1.w + b4.w, 0.0f);
    ((float4*)out)[(r0 + rg*2    )*64 + colblk*32 + cb] = o0;
    ((float4*)out)[(r0 + rg*2 + 1)*64 + colblk*32 + cb] = o1;
}

// ---------------------------------------------------------------------------
extern "C" void kernel_launch(void* const* d_in, const int* in_sizes, int n_in,
                              void* d_out, int out_size, void* d_ws, size_t ws_size,
                              hipStream_t stream)
{
    (void)in_sizes; (void)n_in; (void)out_size; (void)ws_size;
    const float* verts = (const float*)d_in[0];
    const float* x     = (const float*)d_in[1];
    const float* convW = (const float*)d_in[2];
    const float* convB = (const float*)d_in[3];
    const float* dirs  = (const float*)d_in[4];
    const float* gam   = (const float*)d_in[5];
    const float* bet   = (const float*)d_in[6];
    const float* dW    = (const float*)d_in[7];
    const float* db    = (const float*)d_in[8];
    float* out = (float*)d_out;

    char* ws = (char*)d_ws;
    int*   idxb = (int*)(ws);
    float* sdn  = (float*)(ws + 819200);
    float* stp  = (float*)(ws + 828416);         // 6 x 32 x 256 f32
    float* fo   = (float*)(ws + 1025024);        // 3 x (2048,256)
    float* pb   = (float*)(ws + 7316480);        // p_k = pb + k*262144

    float* p0 = pb,            *p1 = pb + 262144,   *p2 = pb + 2*262144;
    float* p3 = pb + 3*262144, *p4 = pb + 4*262144, *p5 = pb + 5*262144;
    float* stL0 = stp,         *stL1 = stp + 8192,  *stL2 = stp + 16384;
    float* stL3 = stp + 24576, *stL4 = stp + 32768, *stL5 = stp + 40960;
    const float* nf = (const float*)0;
    float* nw = (float*)0;

    // K1: knn + gemmA (L0->fo0, L1->fo1, L3->fo2) + zero stp + dirs norm
    k1_kernel<<<1473, 256, 0, stream>>>(verts, dirs, x, convW, convB,
                                        idxb, sdn, stp, fo);
    // K2: aggA -> p3 (n100, fo2, d3) [y=0, dispatches first], p1 (n20, fo1, d1)
    //     (p0-agg deferred to K6: fo0 preserved; K2 = 2048 blocks, one pass)
    agg_kernel<<<dim3(1024,2), 256, 0, stream>>>(
        idxb, verts, sdn, fo, 100, 20, 0, 3, 1, 0, 2, 1, 0,
        p3, p1, nw, stL3, stL1, nw);
    // K3: gemmB: L2 = bn(p1)@W2 -> fo2 ; L4 = bn(p3)@W4 -> fo1
    gemm2_kernel<<<dim3(256,2), 256, 0, stream>>>(
        p1, stL1, gam + 128, bet + 128, convW + 65536,  convB + 512,  fo + 2*524288,
        p3, stL3, gam + 384, bet + 384, convW + 131072, convB + 1024, fo + 524288);
    // K4: aggB -> p4 (n100, fo1, d4) [y=0], p2 (n20, fo2, d2)
    agg_kernel<<<dim3(1024,2), 256, 0, stream>>>(
        idxb, verts, sdn, fo, 100, 20, 0, 4, 2, 0, 1, 2, 0,
        p4, p2, nw, stL4, stL2, nw);
    // K5: gemmC: L5 = bn(p4)@W3 -> fo1
    gemm2_kernel<<<dim3(256,1), 256, 0, stream>>>(
        p4, stL4, gam + 512, bet + 512, convW + 98304, convB + 768, fo + 524288,
        nf, nf, nf, nf, nf, nf, nw);
    // K6: aggC -> p5 (n100, fo1, d3) [y=0] + deferred p0 (n5, fo0, d0)
    agg_kernel<<<dim3(1024,2), 256, 0, stream>>>(
        idxb, verts, sdn, fo, 100, 5, 0, 3, 0, 0, 1, 0, 0,
        p5, p0, nw, stL5, stL0, nw);
    // K7: down: bn(p0,stL0,g0,b0) | bn(p2,stL2,g2,b2) | bn(p5,stL5,g3,b3)
    down_kernel<<<dim3(128,2), 256, 0, stream>>>(
        p0, stL0, gam, bet,
        p2, stL2, gam + 256, bet + 256,
        p5, stL5, gam + 384, bet + 384,
        dW, db, out);
}

// Round 7
// 173.414 us; speedup vs baseline: 4.2419x; 1.0127x over previous
//
#include <hip/hip_runtime.h>

// ---------------------------------------------------------------------------
// Workspace:
//   idxb 0        : (2048,100) int       819200
//   sdn  819200   : (6,3,128)              9216
//   stp  828416   : 6 layers x 32 banks x 256 f32  196608   (BN partials)
//   fo   1025024  : 3 x (2048,256)       6291456
//   p0.. 7316480  : 6 x (2048,128)       6291456
// r7 = r6 (175.6us verified) + two micro-opts:
//   (a) knn survivor-compaction: wave prefix-scan instead of 1024 serialized
//       same-address LDS atomics on sel[3]
//   (b) agg: premultiplied row offsets (js = row<<8) + hoisted base pointer
//       kills the per-neighbor 64-bit mad
// Schedule (verified r6): K1 knn+gemmA | K2 agg(p3,p1) | K3 gemm(L2,L4) |
//   K4 agg(p4,p2) | K5 gemm(L5) | K6 agg(p5,p0) | K7 down.
// [r5 lesson: cooperative fusion = 620us. Multi-launch is right.]
// [r1 lesson: no reg-prefetch across barriers. r3 lesson: keep scalar agg.]
// ---------------------------------------------------------------------------

// ---------------------------------------------------------------------------
// GEMM body (chunked-LDS W, 16KB chunks): used only inside k1 (LDS capped
// at 21.5KB so knn blocks keep ~7 blocks/CU; gemm latency hidden by
// co-resident knn blocks).
// ---------------------------------------------------------------------------
__device__ __forceinline__ void do_gemm(
    const float* __restrict__ in, const float* __restrict__ stp,
    const float* __restrict__ gm, const float* __restrict__ bt,
    const float* __restrict__ W, const float* __restrict__ bi,
    float* __restrict__ out, int rb, char* smemc)
{
    float* rows  = (float*)smemc;           // 1024 floats
    float* wch   = rows + 1024;             // 4096 floats (16 KB)
    float* scale = wch + 4096;              // 128
    float* shift = scale + 128;             // 128
    int t = threadIdx.x;
    if (t < 128) {
        float sc = 1.0f, sf = 0.0f;
        if (stp) {
            float sm = 0.0f, sq = 0.0f;
            #pragma unroll 8
            for (int bk = 0; bk < 32; ++bk) {
                sm += stp[bk*256 + t];
                sq += stp[bk*256 + 128 + t];
            }
            float mu  = sm * (1.0f/2048.0f);
            float var = sq * (1.0f/2048.0f) - mu*mu;
            sc = rsqrtf(var + 1e-5f) * gm[t];
            sf = bt[t] - mu*sc;
        }
        scale[t] = sc; shift[t] = sf;
    }
    __syncthreads();
    int r0 = rb * 8;
    {
        float4 v = ((const float4*)(in + r0*128))[t];
        if (stp) {
            int c4 = (t & 31) << 2;
            v.x = fmaxf(v.x*scale[c4  ] + shift[c4  ], 0.0f);
            v.y = fmaxf(v.y*scale[c4+1] + shift[c4+1], 0.0f);
            v.z = fmaxf(v.z*scale[c4+2] + shift[c4+2], 0.0f);
            v.w = fmaxf(v.w*scale[c4+3] + shift[c4+3], 0.0f);
        }
        ((float4*)rows)[t] = v;
    }
    int cb = t & 63, rp = (t >> 6) << 1;
    const float* a0r = rows + rp*128;
    const float* a1r = a0r + 128;
    const float4* W4 = (const float4*)W;
    float4* wch4 = (float4*)wch;
    float4 acc0 = make_float4(0.f,0.f,0.f,0.f);
    float4 acc1 = make_float4(0.f,0.f,0.f,0.f);
    for (int c = 0; c < 8; ++c) {
        __syncthreads();
        #pragma unroll
        for (int i = 0; i < 4; ++i)
            wch4[t + 256*i] = W4[c*1024 + t + 256*i];
        __syncthreads();
        int kb = c*16;
        #pragma unroll
        for (int k = 0; k < 16; k += 4) {
            float4 a0 = *(const float4*)(a0r + kb + k);
            float4 a1 = *(const float4*)(a1r + kb + k);
            float4 w;
            w = wch4[(k+0)*64+cb];
            acc0.x += a0.x*w.x; acc0.y += a0.x*w.y; acc0.z += a0.x*w.z; acc0.w += a0.x*w.w;
            acc1.x += a1.x*w.x; acc1.y += a1.x*w.y; acc1.z += a1.x*w.z; acc1.w += a1.x*w.w;
            w = wch4[(k+1)*64+cb];
            acc0.x += a0.y*w.x; acc0.y += a0.y*w.y; acc0.z += a0.y*w.z; acc0.w += a0.y*w.w;
            acc1.x += a1.y*w.x; acc1.y += a1.y*w.y; acc1.z += a1.y*w.z; acc1.w += a1.y*w.w;
            w = wch4[(k+2)*64+cb];
            acc0.x += a0.z*w.x; acc0.y += a0.z*w.y; acc0.z += a0.z*w.z; acc0.w += a0.z*w.w;
            acc1.x += a1.z*w.x; acc1.y += a1.z*w.y; acc1.z += a1.z*w.z; acc1.w += a1.z*w.w;
            w = wch4[(k+3)*64+cb];
            acc0.x += a0.w*w.x; acc0.y += a0.w*w.y; acc0.z += a0.w*w.z; acc0.w += a0.w*w.w;
            acc1.x += a1.w*w.x; acc1.y += a1.w*w.y; acc1.z += a1.w*w.z; acc1.w += a1.w*w.w;
        }
    }
    float4 b4 = ((const float4*)bi)[cb];
    acc0.x += b4.x; acc0.y += b4.y; acc0.z += b4.z; acc0.w += b4.w;
    acc1.x += b4.x; acc1.y += b4.y; acc1.z += b4.z; acc1.w += b4.w;
    ((float4*)out)[(r0+rp  )*64 + cb] = acc0;
    ((float4*)out)[(r0+rp+1)*64 + cb] = acc1;
}

// ---------------------------------------------------------------------------
// Big-chunk GEMM body (K3/K5): chunk = k64 (64KB), 2 chunks -> 4x fewer
// exposed load-latency boundaries. LDS 69KB; 2 blocks/CU for K3.
// ---------------------------------------------------------------------------
__device__ __forceinline__ void do_gemm_big(
    const float* __restrict__ in, const float* __restrict__ stp,
    const float* __restrict__ gm, const float* __restrict__ bt,
    const float* __restrict__ W, const float* __restrict__ bi,
    float* __restrict__ out, int rb, char* smemc)
{
    float* rows  = (float*)smemc;           // 1024 floats
    float* wch   = rows + 1024;             // 16384 floats (64 KB)
    float* scale = wch + 16384;             // 128
    float* shift = scale + 128;             // 128
    int t = threadIdx.x;
    if (t < 128) {
        float sc = 1.0f, sf = 0.0f;
        if (stp) {
            float sm = 0.0f, sq = 0.0f;
            #pragma unroll 8
            for (int bk = 0; bk < 32; ++bk) {
                sm += stp[bk*256 + t];
                sq += stp[bk*256 + 128 + t];
            }
            float mu  = sm * (1.0f/2048.0f);
            float var = sq * (1.0f/2048.0f) - mu*mu;
            sc = rsqrtf(var + 1e-5f) * gm[t];
            sf = bt[t] - mu*sc;
        }
        scale[t] = sc; shift[t] = sf;
    }
    __syncthreads();
    int r0 = rb * 8;
    {
        float4 v = ((const float4*)(in + r0*128))[t];
        if (stp) {
            int c4 = (t & 31) << 2;
            v.x = fmaxf(v.x*scale[c4  ] + shift[c4  ], 0.0f);
            v.y = fmaxf(v.y*scale[c4+1] + shift[c4+1], 0.0f);
            v.z = fmaxf(v.z*scale[c4+2] + shift[c4+2], 0.0f);
            v.w = fmaxf(v.w*scale[c4+3] + shift[c4+3], 0.0f);
        }
        ((float4*)rows)[t] = v;
    }
    int cb = t & 63, rp = (t >> 6) << 1;
    const float* a0r = rows + rp*128;
    const float* a1r = a0r + 128;
    const float4* W4 = (const float4*)W;   // [128][64] f4
    float4* wch4 = (float4*)wch;           // [64][64] f4 per chunk
    float4 acc0 = make_float4(0.f,0.f,0.f,0.f);
    float4 acc1 = make_float4(0.f,0.f,0.f,0.f);
    for (int c = 0; c < 2; ++c) {
        __syncthreads();
        #pragma unroll
        for (int i = 0; i < 16; ++i)
            wch4[t + 256*i] = W4[c*4096 + t + 256*i];
        __syncthreads();
        int kb = c*64;
        #pragma unroll 4
        for (int k = 0; k < 64; k += 4) {
            float4 a0 = *(const float4*)(a0r + kb + k);
            float4 a1 = *(const float4*)(a1r + kb + k);
            float4 w;
            w = wch4[(k+0)*64+cb];
            acc0.x += a0.x*w.x; acc0.y += a0.x*w.y; acc0.z += a0.x*w.z; acc0.w += a0.x*w.w;
            acc1.x += a1.x*w.x; acc1.y += a1.x*w.y; acc1.z += a1.x*w.z; acc1.w += a1.x*w.w;
            w = wch4[(k+1)*64+cb];
            acc0.x += a0.y*w.x; acc0.y += a0.y*w.y; acc0.z += a0.y*w.z; acc0.w += a0.y*w.w;
            acc1.x += a1.y*w.x; acc1.y += a1.y*w.y; acc1.z += a1.y*w.z; acc1.w += a1.y*w.w;
            w = wch4[(k+2)*64+cb];
            acc0.x += a0.z*w.x; acc0.y += a0.z*w.y; acc0.z += a0.z*w.z; acc0.w += a0.z*w.w;
            acc1.x += a1.z*w.x; acc1.y += a1.z*w.y; acc1.z += a1.z*w.z; acc1.w += a1.z*w.w;
            w = wch4[(k+3)*64+cb];
            acc0.x += a0.w*w.x; acc0.y += a0.w*w.y; acc0.z += a0.w*w.z; acc0.w += a0.w*w.w;
            acc1.x += a1.w*w.x; acc1.y += a1.w*w.y; acc1.z += a1.w*w.z; acc1.w += a1.w*w.w;
        }
    }
    float4 b4 = ((const float4*)bi)[cb];
    acc0.x += b4.x; acc0.y += b4.y; acc0.z += b4.z; acc0.w += b4.w;
    acc1.x += b4.x; acc1.y += b4.y; acc1.z += b4.z; acc1.w += b4.w;
    ((float4*)out)[(r0+rp  )*64 + cb] = acc0;
    ((float4*)out)[(r0+rp+1)*64 + cb] = acc1;
}

// ---------------------------------------------------------------------------
// K1: wave-sync knn (0..511) + gemmA (512..1279) + zero stp (1280..1471) +
// dirs norm (1472). knn verified r8-r12; r7: scan-based compaction.
// ---------------------------------------------------------------------------
__global__ void k1_kernel(const float* __restrict__ verts, const float* __restrict__ dirs,
                          const float* __restrict__ x,
                          const float* __restrict__ convW, const float* __restrict__ convB,
                          int* __restrict__ idxout, float* __restrict__ sdn,
                          float* __restrict__ stp, float* __restrict__ fo)
{
    __shared__ __align__(16) char smem[21504];
    int t = threadIdx.x;
    int blk = blockIdx.x;

    if (blk >= 1280) {
        if (blk == 1472) {
            for (int i = t; i < 768; i += 256) {
                int l = i >> 7, k = i & 127;
                float a = dirs[l*384 + k];
                float b = dirs[l*384 + 128 + k];
                float c = dirs[l*384 + 256 + k];
                float nrm = sqrtf(a*a + b*b + c*c);
                float inv = 1.0f / fmaxf(nrm, 1e-12f);
                sdn[l*384 + k]       = a*inv;
                sdn[l*384 + 128 + k] = b*inv;
                sdn[l*384 + 256 + k] = c*inv;
            }
        } else {
            stp[(blk - 1280)*256 + t] = 0.0f;     // 192 blocks x 256 = 49152
        }
        return;
    }
    if (blk >= 512) {
        int g = blk - 512;
        int s = g >> 8, rb = g & 255;
        int wi = (s==0) ? 0 : (s==1) ? 1 : 3;
        do_gemm(x, (const float*)0, (const float*)0, (const float*)0,
                convW + wi*32768, convB + wi*256, fo + s*524288, rb, smem);
        return;
    }

    // ---------------- knn: one wave per vertex ----------------
    float* xs  = (float*)smem;
    float* ys  = xs + 1024;
    float* zs  = ys + 1024;
    float* sqs = zs + 1024;
    unsigned int* histBase = (unsigned int*)(smem + 16384);
    unsigned int* selBase  = (unsigned int*)(smem + 20480);

    int w = t >> 6, l = t & 63;
    int vglob = blk*4 + w;
    int b = vglob >> 10;
    int v = vglob & 1023;
    unsigned long long* keys = (unsigned long long*)smem + w*256;  // alias xs/ys
    unsigned int* hist = histBase + w*256;
    unsigned int* sel  = selBase + w*4;

    const float* vb = verts + b * 3072;
    for (int i = t; i < 1024; i += 256) {
        float xx = vb[i*3+0], yy = vb[i*3+1], zz = vb[i*3+2];
        xs[i] = xx; ys[i] = yy; zs[i] = zz;
        sqs[i] = xx*xx + yy*yy + zz*zz;
    }
    __syncthreads();

    float cx = xs[v], cy = ys[v], cz = zs[v], csq = sqs[v];
    unsigned long long K16[16];
    #pragma unroll
    for (int q = 0; q < 16; ++q) {
        int j = q*64 + l;
        float dot = cx*xs[j] + cy*ys[j] + cz*zs[j];
        float d = -2.0f*dot + csq + sqs[j];
        unsigned int u = __float_as_uint(d);
        u = (u & 0x80000000u) ? ~u : (u | 0x80000000u);
        K16[q] = (((unsigned long long)u) << 32) | (unsigned long long)j;
    }
    #pragma unroll
    for (int i = 0; i < 4; ++i) hist[l*4 + i] = 0u;
    __syncthreads();

    #pragma unroll
    for (int q = 0; q < 16; ++q)
        atomicAdd(&hist[(unsigned int)(K16[q] >> 56)], 1u);
    __syncthreads();

    {
        unsigned int h0 = hist[l*4], h1 = hist[l*4+1], h2 = hist[l*4+2], h3 = hist[l*4+3];
        unsigned int c1 = h0, c2 = h0+h1, c3 = h0+h1+h2, T = c3+h3;
        unsigned int xacc = T;
        #pragma unroll
        for (int off = 1; off < 64; off <<= 1) {
            unsigned int y = __shfl_up(xacc, off, 64);
            if (l >= off) xacc += y;
        }
        unsigned int P = xacc - T;
        unsigned int ex[4] = {P, P+c1, P+c2, P+c3};
        unsigned int hh[4] = {h0, h1, h2, h3};
        #pragma unroll
        for (int i = 0; i < 4; ++i) {
            if (ex[i] < 101u && ex[i] + hh[i] >= 101u) {
                sel[0] = (unsigned int)(l*4 + i);
                sel[1] = 101u - ex[i];
            }
        }
    }
    __syncthreads();
    unsigned int P8 = sel[0], rank2 = sel[1];
    #pragma unroll
    for (int i = 0; i < 4; ++i) hist[l*4 + i] = 0u;
    __syncthreads();

    #pragma unroll
    for (int q = 0; q < 16; ++q)
        if ((unsigned int)(K16[q] >> 56) == P8)
            atomicAdd(&hist[(unsigned int)(K16[q] >> 48) & 0xFFu], 1u);
    __syncthreads();

    {
        unsigned int h0 = hist[l*4], h1 = hist[l*4+1], h2 = hist[l*4+2], h3 = hist[l*4+3];
        unsigned int c1 = h0, c2 = h0+h1, c3 = h0+h1+h2, T = c3+h3;
        unsigned int xacc = T;
        #pragma unroll
        for (int off = 1; off < 64; off <<= 1) {
            unsigned int y = __shfl_up(xacc, off, 64);
            if (l >= off) xacc += y;
        }
        unsigned int P = xacc - T;
        unsigned int ex[4] = {P, P+c1, P+c2, P+c3};
        unsigned int hh[4] = {h0, h1, h2, h3};
        #pragma unroll
        for (int i = 0; i < 4; ++i) {
            if (ex[i] < rank2 && ex[i] + hh[i] >= rank2) {
                sel[2] = (P8 << 8) | (unsigned int)(l*4 + i);
            }
        }
    }
    __syncthreads();
    unsigned int P16 = sel[2];

    // r7: survivor compaction via wave prefix-scan (was: up to 1024
    // serialized same-address LDS atomics on sel[3]).
    unsigned int ccnt = 0u;
    #pragma unroll
    for (int q = 0; q < 16; ++q)
        if ((unsigned int)(K16[q] >> 48) <= P16) ++ccnt;
    unsigned int inc = ccnt;
    #pragma unroll
    for (int off = 1; off < 64; off <<= 1) {
        unsigned int y = __shfl_up(inc, off, 64);
        if (l >= off) inc += y;
    }
    unsigned int wpos = inc - ccnt;
    unsigned int cnt  = (unsigned int)__shfl((int)inc, 63, 64);
    #pragma unroll
    for (int q = 0; q < 16; ++q) {
        if ((unsigned int)(K16[q] >> 48) <= P16) {
            if (wpos < 256u) keys[wpos] = K16[q];
            ++wpos;
        }
    }
    __syncthreads();

    unsigned long long K[4];
    #pragma unroll
    for (int q = 0; q < 4; ++q) {
        unsigned int e = (unsigned int)(l*4 + q);
        K[q] = (e < cnt) ? keys[e] : 0xFFFFFFFFFFFFFFFFULL;
    }

    auto cswap = [&](int qa, int qb, int k) {
        int e = (l << 2) + qa;
        bool up = ((e & k) == 0);
        unsigned long long a = K[qa], bb2 = K[qb];
        unsigned long long mn = a < bb2 ? a : bb2;
        unsigned long long mx = a < bb2 ? bb2 : a;
        K[qa] = up ? mn : mx;
        K[qb] = up ? mx : mn;
    };
    #pragma unroll
    for (int k = 2; k <= 256; k <<= 1) {
        for (int j = k >> 1; j >= 4; j >>= 1) {
            int lj = j >> 2;
            #pragma unroll
            for (int q = 0; q < 4; ++q) {
                unsigned long long other = __shfl_xor(K[q], lj, 64);
                int e = (l << 2) + q;
                bool up = ((e & k) == 0);
                bool lower = ((l & lj) == 0);
                bool takeMin = (lower == up);
                unsigned long long mn = K[q] < other ? K[q] : other;
                unsigned long long mx = K[q] < other ? other : K[q];
                K[q] = takeMin ? mn : mx;
            }
        }
        if (k >= 4) { cswap(0, 2, k); cswap(1, 3, k); }
        cswap(0, 1, k); cswap(2, 3, k);
    }

    #pragma unroll
    for (int q = 0; q < 4; ++q) {
        int e = l*4 + q;
        if (e >= 1 && e <= 100)
            idxout[vglob*100 + (e-1)] = (int)(K[q] & 0xFFFFFFFFu);
    }
}

// ---------------------------------------------------------------------------
// Agg + fused BN-partials (r2 scalar body + r7 premult addressing).
// grid (1024, nslots); per-slot fo index f0/f1/f2. 256 thr = 2 rows.
// ---------------------------------------------------------------------------
__global__ void agg_kernel(const int* __restrict__ idx, const float* __restrict__ verts,
                           const float* __restrict__ sdn, const float* __restrict__ fo,
                           int n0, int n1, int n2, int d0, int d1, int d2,
                           int f0, int f1, int f2,
                           float* o0, float* o1, float* o2,
                           float* s0p, float* s1p, float* s2p)
{
    __shared__ float4 ds4s[200];
    __shared__ int jss[200];
    int slot = blockIdx.y;
    int n  = slot==0 ? n0 : slot==1 ? n1 : n2;
    int dI = slot==0 ? d0 : slot==1 ? d1 : d2;
    int fI = slot==0 ? f0 : slot==1 ? f1 : f2;
    float* outp = slot==0 ? o0 : slot==1 ? o1 : o2;
    float* stp  = slot==0 ? s0p : slot==1 ? s1p : s2p;
    const float* fos = fo + fI * 524288;
    const float* sd = sdn + dI * 384;

    int t = threadIdx.x;
    int h = t >> 7, tt = t & 127;
    float4* ds4 = ds4s + h*100;
    int* js = jss + h*100;
    int r = blockIdx.x*2 + h;
    int b = r >> 10;

    if (tt < n) {
        int j = idx[r*100 + tt];
        js[tt] = ((b << 10) + j) << 8;      // premultiplied fo-row offset (r7)
        const float* pj = verts + ((b << 10) + j)*3;
        const float* pv = verts + r*3;
        float dx = pj[0]-pv[0], dy = pj[1]-pv[1], dz = pj[2]-pv[2];
        float nm = sqrtf(dx*dx + dy*dy + dz*dz);
        float inv = 1.0f / fmaxf(nm, 1e-12f);
        ds4[tt] = make_float4(dx*inv, dy*inv, dz*inv, 0.0f);
    }
    __syncthreads();
    float s0 = sd[tt], s1 = sd[128+tt], s2 = sd[256+tt];
    const float* fbase = fos + 128 + tt;    // hoisted base (r7)
    float m = -3.0e38f;
    for (int q = 0; q < n; q += 5) {
        float th[5];
        const float* p[5];
        #pragma unroll
        for (int u = 0; u < 5; ++u) {
            float4 dq = ds4[q+u];
            th[u] = fmaxf(dq.x*s0 + dq.y*s1 + dq.z*s2, 0.0f);
            p[u] = fbase + js[q+u];
        }
        float vv[5];
        #pragma unroll
        for (int u = 0; u < 5; ++u) vv[u] = *p[u];
        #pragma unroll
        for (int u = 0; u < 5; ++u) m = fmaxf(m, th[u]*vv[u]);
    }
    float val = fos[r*256 + tt] + m;
    outp[r*128 + tt] = val;
    float* bank = stp + (r & 31)*256;
    atomicAdd(&bank[tt], val);
    atomicAdd(&bank[128+tt], val*val);
}

// ---------------------------------------------------------------------------
// Standalone gemm (big-chunk body), up to 2 slots via blockIdx.y.
// grid (256, nslots), 256 thr. LDS 69KB -> 2 blocks/CU for K3.
// ---------------------------------------------------------------------------
__global__ void gemm2_kernel(
    const float* inA, const float* stA, const float* gA, const float* beA,
    const float* WA, const float* biA, float* foA,
    const float* inB, const float* stB, const float* gB, const float* beB,
    const float* WB, const float* biB, float* foB)
{
    __shared__ __align__(16) char smem[70656];
    if (blockIdx.y == 0)
        do_gemm_big(inA, stA, gA, beA, WA, biA, foA, blockIdx.x, smem);
    else
        do_gemm_big(inB, stB, gB, beB, WB, biB, foB, blockIdx.x, smem);
}

// ---------------------------------------------------------------------------
// Down-proj: [bn(p0)|bn(p1)|bn(p2)] (384) @ dW + db, relu.
// 16 rows x 128 cols per block, grid (128,2) = 256 blocks.
// W slice per block = 384x128 in 3 chunks of k=128 (64KB each). LDS 91KB.
// ---------------------------------------------------------------------------
__global__ void down_kernel(
    const float* __restrict__ p0, const float* __restrict__ s0p,
    const float* __restrict__ g0, const float* __restrict__ be0,
    const float* __restrict__ p1, const float* __restrict__ s1p,
    const float* __restrict__ g1, const float* __restrict__ be1,
    const float* __restrict__ p2, const float* __restrict__ s2p,
    const float* __restrict__ g2, const float* __restrict__ be2,
    const float* __restrict__ dW, const float* __restrict__ db,
    float* __restrict__ out)
{
    __shared__ __align__(16) float rows[16*384];      // 24 KB
    __shared__ __align__(16) float4 wch4[4096];       // 64 KB  [k=128][cb=32]
    __shared__ float scale[384], shift[384];
    int t = threadIdx.x;
    int r0 = blockIdx.x * 16;
    int colblk = blockIdx.y;                          // 0 or 1

    for (int c = t; c < 384; c += 256) {
        int seg = c >> 7, cc = c & 127;
        const float* stp = seg==0 ? s0p : seg==1 ? s1p : s2p;
        const float* g   = seg==0 ? g0  : seg==1 ? g1  : g2;
        const float* be  = seg==0 ? be0 : seg==1 ? be1 : be2;
        float sm = 0.0f, sq = 0.0f;
        #pragma unroll 8
        for (int bk = 0; bk < 32; ++bk) {
            sm += stp[bk*256 + cc];
            sq += stp[bk*256 + 128 + cc];
        }
        float mu  = sm * (1.0f/2048.0f);
        float var = sq * (1.0f/2048.0f) - mu*mu;
        float s = rsqrtf(var + 1e-5f) * g[cc];
        scale[c] = s;
        shift[c] = be[cc] - mu*s;
    }
    __syncthreads();
    // stage 16 rows x 384 (bn-relu applied): 1536 float4, 6 per thread
    for (int q = t; q < 1536; q += 256) {
        int row = q / 96, rem = q - row*96;
        int c4 = rem << 2;
        int seg = c4 >> 7, cc = c4 & 127;
        const float* ps = seg==0 ? p0 : seg==1 ? p1 : p2;
        float4 v = *(const float4*)(ps + (r0+row)*128 + cc);
        v.x = fmaxf(v.x*scale[c4  ] + shift[c4  ], 0.0f);
        v.y = fmaxf(v.y*scale[c4+1] + shift[c4+1], 0.0f);
        v.z = fmaxf(v.z*scale[c4+2] + shift[c4+2], 0.0f);
        v.w = fmaxf(v.w*scale[c4+3] + shift[c4+3], 0.0f);
        *(float4*)&rows[row*384 + c4] = v;
    }

    int cb = t & 31;
    int rg = t >> 5;
    const float* a0r = rows + (rg*2)*384;
    const float* a1r = a0r + 384;
    const float4* W4 = (const float4*)dW;             // [384][64] f4
    float4 acc0 = make_float4(0.f,0.f,0.f,0.f);
    float4 acc1 = make_float4(0.f,0.f,0.f,0.f);
    for (int c = 0; c < 3; ++c) {
        __syncthreads();   // rows staged (c=0) / chunk c-1 fully consumed
        #pragma unroll
        for (int i = 0; i < 16; ++i) {
            int e = t + 256*i;                        // 0..4095
            wch4[e] = W4[c*8192 + colblk*32 + (e >> 5)*64 + (e & 31)];
        }
        __syncthreads();
        int kb = c*128;
        #pragma unroll 8
        for (int k = 0; k < 128; k += 4) {
            float4 a0 = *(const float4*)(a0r + kb + k);
            float4 a1 = *(const float4*)(a1r + kb + k);
            float4 w;
            w = wch4[(k+0)*32+cb];
            acc0.x += a0.x*w.x; acc0.y += a0.x*w.y; acc0.z += a0.x*w.z; acc0.w += a0.x*w.w;
            acc1.x += a1.x*w.x; acc1.y += a1.x*w.y; acc1.z += a1.x*w.z; acc1.w += a1.x*w.w;
            w = wch4[(k+1)*32+cb];
            acc0.x += a0.y*w.x; acc0.y += a0.y*w.y; acc0.z += a0.y*w.z; acc0.w += a0.y*w.w;
            acc1.x += a1.y*w.x; acc1.y += a1.y*w.y; acc1.z += a1.y*w.z; acc1.w += a1.y*w.w;
            w = wch4[(k+2)*32+cb];
            acc0.x += a0.z*w.x; acc0.y += a0.z*w.y; acc0.z += a0.z*w.z; acc0.w += a0.z*w.w;
            acc1.x += a1.z*w.x; acc1.y += a1.z*w.y; acc1.z += a1.z*w.z; acc1.w += a1.z*w.w;
            w = wch4[(k+3)*32+cb];
            acc0.x += a0.w*w.x; acc0.y += a0.w*w.y; acc0.z += a0.w*w.z; acc0.w += a0.w*w.w;
            acc1.x += a1.w*w.x; acc1.y += a1.w*w.y; acc1.z += a1.w*w.z; acc1.w += a1.w*w.w;
        }
    }
    float4 b4 = ((const float4*)db)[colblk*32 + cb];
    float4 o0, o1;
    o0.x = fmaxf(acc0.x + b4.x, 0.0f); o0.y = fmaxf(acc0.y + b4.y, 0.0f);
    o0.z = fmaxf(acc0.z + b4.z, 0.0f); o0.w = fmaxf(acc0.w + b4.w, 0.0f);
    o1.x = fmaxf(acc1.x + b4.x, 0.0f); o1.y = fmaxf(acc1.y + b4.y, 0.0f);
    o1.z = fmaxf(acc1.z + b4.z, 0.0f); o1.w = fmaxf(acc1.w + b4.w, 0.0f);
    ((float4*)out)[(r0 + rg*2    )*64 + colblk*32 + cb] = o0;
    ((float4*)out)[(r0 + rg*2 + 1)*64 + colblk*32 + cb] = o1;
}

// ---------------------------------------------------------------------------
extern "C" void kernel_launch(void* const* d_in, const int* in_sizes, int n_in,
                              void* d_out, int out_size, void* d_ws, size_t ws_size,
                              hipStream_t stream)
{
    (void)in_sizes; (void)n_in; (void)out_size; (void)ws_size;
    const float* verts = (const float*)d_in[0];
    const float* x     = (const float*)d_in[1];
    const float* convW = (const float*)d_in[2];
    const float* convB = (const float*)d_in[3];
    const float* dirs  = (const float*)d_in[4];
    const float* gam   = (const float*)d_in[5];
    const float* bet   = (const float*)d_in[6];
    const float* dW    = (const float*)d_in[7];
    const float* db    = (const float*)d_in[8];
    float* out = (float*)d_out;

    char* ws = (char*)d_ws;
    int*   idxb = (int*)(ws);
    float* sdn  = (float*)(ws + 819200);
    float* stp  = (float*)(ws + 828416);         // 6 x 32 x 256 f32
    float* fo   = (float*)(ws + 1025024);        // 3 x (2048,256)
    float* pb   = (float*)(ws + 7316480);        // p_k = pb + k*262144

    float* p0 = pb,            *p1 = pb + 262144,   *p2 = pb + 2*262144;
    float* p3 = pb + 3*262144, *p4 = pb + 4*262144, *p5 = pb + 5*262144;
    float* stL0 = stp,         *stL1 = stp + 8192,  *stL2 = stp + 16384;
    float* stL3 = stp + 24576, *stL4 = stp + 32768, *stL5 = stp + 40960;
    const float* nf = (const float*)0;
    float* nw = (float*)0;

    // K1: knn + gemmA (L0->fo0, L1->fo1, L3->fo2) + zero stp + dirs norm
    k1_kernel<<<1473, 256, 0, stream>>>(verts, dirs, x, convW, convB,
                                        idxb, sdn, stp, fo);
    // K2: aggA -> p3 (n100, fo2, d3) [y=0, first], p1 (n20, fo1, d1)
    agg_kernel<<<dim3(1024,2), 256, 0, stream>>>(
        idxb, verts, sdn, fo, 100, 20, 0, 3, 1, 0, 2, 1, 0,
        p3, p1, nw, stL3, stL1, nw);
    // K3: gemmB: L2 = bn(p1)@W2 -> fo2 ; L4 = bn(p3)@W4 -> fo1
    gemm2_kernel<<<dim3(256,2), 256, 0, stream>>>(
        p1, stL1, gam + 128, bet + 128, convW + 65536,  convB + 512,  fo + 2*524288,
        p3, stL3, gam + 384, bet + 384, convW + 131072, convB + 1024, fo + 524288);
    // K4: aggB -> p4 (n100, fo1, d4) [y=0], p2 (n20, fo2, d2)
    agg_kernel<<<dim3(1024,2), 256, 0, stream>>>(
        idxb, verts, sdn, fo, 100, 20, 0, 4, 2, 0, 1, 2, 0,
        p4, p2, nw, stL4, stL2, nw);
    // K5: gemmC: L5 = bn(p4)@W3 -> fo1
    gemm2_kernel<<<dim3(256,1), 256, 0, stream>>>(
        p4, stL4, gam + 512, bet + 512, convW + 98304, convB + 768, fo + 524288,
        nf, nf, nf, nf, nf, nf, nw);
    // K6: aggC -> p5 (n100, fo1, d3) [y=0] + deferred p0 (n5, fo0, d0)
    agg_kernel<<<dim3(1024,2), 256, 0, stream>>>(
        idxb, verts, sdn, fo, 100, 5, 0, 3, 0, 0, 1, 0, 0,
        p5, p0, nw, stL5, stL0, nw);
    // K7: down: bn(p0,stL0,g0,b0) | bn(p2,stL2,g2,b2) | bn(p5,stL5,g3,b3)
    down_kernel<<<dim3(128,2), 256, 0, stream>>>(
        p0, stL0, gam, bet,
        p2, stL2, gam + 256, bet + 256,
        p5, stL5, gam + 384, bet + 384,
        dW, db, out);
}